// Round 11
// baseline (616.776 us; speedup 1.0000x reference)
//
#include <hip/hip_runtime.h>

#define B_   2
#define L_   2048
#define H_   1024
#define NH_  16
#define KVH_ 4
#define HD_  64

typedef short short8 __attribute__((ext_vector_type(8)));
typedef float f32x4 __attribute__((ext_vector_type(4)));
typedef float f32x16 __attribute__((ext_vector_type(16)));
typedef unsigned short u16x4 __attribute__((ext_vector_type(4)));

#define LOG2E 1.4426950408889634f
#define QSC   0.18033688011112042f   /* 0.125 * log2(e) */
#define MFMA   __builtin_amdgcn_mfma_f32_16x16x32_bf16
#define MFMA32 __builtin_amdgcn_mfma_f32_32x32x16_bf16

#if __has_builtin(__builtin_amdgcn_exp2f)
#define EXP2(x) __builtin_amdgcn_exp2f(x)
#else
#define EXP2(x) exp2f(x)
#endif

static __device__ __forceinline__ unsigned short f2bf(float f) {
  unsigned int u = __float_as_uint(f);
  u += 0x7FFFu + ((u >> 16) & 1u);
  return (unsigned short)(u >> 16);
}

static __device__ __forceinline__ unsigned int cvtpk(float lo, float hi) {
  unsigned int r;
  asm("v_cvt_pk_bf16_f32 %0, %1, %2" : "=v"(r) : "v"(lo), "v"(hi));
  return r;
}

// dst' = {dst.lo32lanes, src.lo32lanes}, src' = {dst.hi32lanes, src.hi32lanes}
static __device__ __forceinline__ void plswap(unsigned int& a, unsigned int& b) {
  asm("v_permlane32_swap_b32 %0, %1" : "+v"(a), "+v"(b));
}

static __device__ __forceinline__ short8 mk8(unsigned int w0, unsigned int w1,
                                             unsigned int w2, unsigned int w3) {
  union { unsigned int u[4]; short8 s; } x;
  x.u[0] = w0; x.u[1] = w1; x.u[2] = w2; x.u[3] = w3;
  return x.s;
}

static __device__ __forceinline__ void gload_lds16(const void* g, void* l) {
  __builtin_amdgcn_global_load_lds(
      (const __attribute__((address_space(1))) unsigned int*)g,
      (__attribute__((address_space(3))) unsigned int*)l, 16, 0, 0);
}

// ---------------- merged prep: convert x, convert weights, mask scan ----------------
__global__ __launch_bounds__(256) void k_prep(const float* __restrict__ x,
                                              const float* __restrict__ Wq,
                                              const float* __restrict__ Wk,
                                              const float* __restrict__ Wv,
                                              const float* __restrict__ Wo,
                                              const float* __restrict__ mask,
                                              unsigned short* __restrict__ xb,
                                              unsigned short* __restrict__ wcat,
                                              unsigned short* __restrict__ wo_b,
                                              unsigned char* __restrict__ flags) {
  const int blk = blockIdx.x;
  const int t = threadIdx.x;
  if (blk < 4096) {                       // ---- convert x ----
    size_t i = ((size_t)blk * 256 + t) * 4;
    float4 v = *(const float4*)(x + i);
    u16x4 o = { f2bf(v.x), f2bf(v.y), f2bf(v.z), f2bf(v.w) };
    *(u16x4*)(xb + i) = o;
  } else if (blk < 6656) {                // ---- convert weights ----
    int r = blk - 4096;
    int c = t * 4;
    const float* src;
    unsigned short* dst;
    if (r < 1024)      { src = Wq + (size_t)r * 1024;          dst = wcat + (size_t)r * 1024; }
    else if (r < 1280) { src = Wk + (size_t)(r - 1024) * 1024; dst = wcat + (size_t)r * 1024; }
    else if (r < 1536) { src = Wv + (size_t)(r - 1280) * 1024; dst = wcat + (size_t)r * 1024; }
    else               { src = Wo + (size_t)(r - 1536) * 1024; dst = wo_b + (size_t)(r - 1536) * 1024; }
    float4 v = *(const float4*)(src + c);
    u16x4 o = { f2bf(v.x), f2bf(v.y), f2bf(v.z), f2bf(v.w) };
    *(u16x4*)(dst + c) = o;
  } else {                                // ---- mask block-zero scan ----
    const int mb = blk - 6656;            // b*1024 + qb*32 + kb
    const int b = mb >> 10, qb = (mb >> 5) & 31, kb = mb & 31;
    const float* base = mask + ((size_t)b * L_ + qb * 64) * L_ + kb * 64;
    const int r0 = t >> 4, c = (t & 15) * 4;
    bool nz = false;
#pragma unroll
    for (int i = 0; i < 4; ++i) {
      float4 v = *(const float4*)(base + (size_t)(r0 + i * 16) * L_ + c);
      nz |= (v.x != 0.f) | (v.y != 0.f) | (v.z != 0.f) | (v.w != 0.f);
    }
    __shared__ int anyv;
    if (t == 0) anyv = 0;
    __syncthreads();
    if (__any(nz) && (t & 63) == 0) atomicOr(&anyv, 1);
    __syncthreads();
    if (t == 0) flags[mb] = (unsigned char)anyv;
  }
}

// ---------------- GEMM (128x128, BK=64, XOR-swizzle, 2-phase dbuf pipeline) ----------------
template <int MODE>
__global__ __launch_bounds__(256) void k_gemm(const unsigned short* __restrict__ A,
                                              const unsigned short* __restrict__ Bt,
                                              const float* __restrict__ bias0,
                                              const float* __restrict__ bias1,
                                              const float* __restrict__ bias2,
                                              unsigned short* __restrict__ q_ws,
                                              unsigned short* __restrict__ k_ws,
                                              unsigned short* __restrict__ vt_ws,
                                              float* __restrict__ outp) {
  const int bn = blockIdx.x, bm = blockIdx.y;
  const int t = threadIdx.x;
  const int lane = t & 63, li = lane & 15, g = lane >> 4;
  const int wid = t >> 6, wr = wid >> 1, wc = wid & 1;
  __shared__ unsigned short lds_a[2][128 * 64];   // [buf][row][slot], slot s holds G col s^(row&7)
  __shared__ unsigned short lds_b[2][128 * 64];

  const f32x4 z = {0.f, 0.f, 0.f, 0.f};
  f32x4 acc[4][4];
#pragma unroll
  for (int m = 0; m < 4; ++m)
#pragma unroll
    for (int n = 0; n < 4; ++n) acc[m][n] = z;

  // staging: 4 chunks of 256 threads cover 1024 granule-slots (128 rows x 8 slots)
  const unsigned short* asrc[4];
  const unsigned short* bsrc[4];
  int ldst[4];
#pragma unroll
  for (int c = 0; c < 4; ++c) {
    const int idx = c * 256 + t, row = idx >> 3, sl = idx & 7;
    const int gcol = (sl ^ (row & 7)) * 8;
    asrc[c] = A  + (size_t)(bm * 128 + row) * 1024 + gcol;
    bsrc[c] = Bt + (size_t)(bn * 128 + row) * 1024 + gcol;
    ldst[c] = idx * 8;
  }
  const int rs = li & 7;

#define GSTAGE(buf, kc)                                                  \
  {                                                                      \
    _Pragma("unroll")                                                    \
    for (int c = 0; c < 4; ++c) {                                        \
      gload_lds16(asrc[c] + (kc), &lds_a[buf][ldst[c]]);                 \
      gload_lds16(bsrc[c] + (kc), &lds_b[buf][ldst[c]]);                 \
    }                                                                    \
  }

  GSTAGE(0, 0);
  __syncthreads();                        // buf0 ready

#pragma unroll 1
  for (int it = 0; it < 16; ++it) {
    const int cur = it & 1;
    if (it + 1 < 16) GSTAGE(cur ^ 1, (it + 1) * 64);   // issue next tile first (T3-min)
#pragma unroll
    for (int ks = 0; ks < 2; ++ks) {
      short8 af[4], bf[4];
#pragma unroll
      for (int m = 0; m < 4; ++m)
        af[m] = *(const short8*)&lds_a[cur][(wr * 64 + m * 16 + li) * 64 + (((ks * 4 + g) ^ rs) * 8)];
#pragma unroll
      for (int n = 0; n < 4; ++n)
        bf[n] = *(const short8*)&lds_b[cur][(wc * 64 + n * 16 + li) * 64 + (((ks * 4 + g) ^ rs) * 8)];
#pragma unroll
      for (int m = 0; m < 4; ++m)
#pragma unroll
        for (int n = 0; n < 4; ++n)
          acc[m][n] = MFMA(af[m], bf[n], acc[m][n], 0, 0, 0);
    }
    __syncthreads();    // drains this iter's GSTAGE (vmcnt) + all reads of cur (lgkm)
  }
#undef GSTAGE

#pragma unroll
  for (int m = 0; m < 4; ++m) {
    const int row0 = bm * 128 + wr * 64 + m * 16 + 4 * g;
#pragma unroll
    for (int n = 0; n < 4; ++n) {
      const int col = bn * 128 + wc * 64 + n * 16 + li;
      f32x4 v = acc[m][n];
      if (MODE == 1) {
        const float bias = bias0[col];
#pragma unroll
        for (int r = 0; r < 4; ++r) outp[(size_t)(row0 + r) * 1024 + col] = v[r] + bias;
      } else {
        if (col < 1024) {
          const float bias = bias0[col];
#pragma unroll
          for (int r = 0; r < 4; ++r) q_ws[(size_t)(row0 + r) * 1024 + col] = f2bf((v[r] + bias) * QSC);
        } else if (col < 1280) {
          const int cc = col - 1024;
          const float bias = bias1[cc];
#pragma unroll
          for (int r = 0; r < 4; ++r) k_ws[(size_t)(row0 + r) * 256 + cc] = f2bf(v[r] + bias);
        } else {
          const int cc = col - 1280;
          const float bias = bias2[cc];
          const int kvh = cc >> 6, d = cc & 63;
          const int b = row0 >> 11, l0 = row0 & 2047;
          u16x4 pk = { f2bf(v[0] + bias), f2bf(v[1] + bias), f2bf(v[2] + bias), f2bf(v[3] + bias) };
          *(u16x4*)(vt_ws + ((size_t)((b * KVH_ + kvh) * 64 + d)) * 2048 + l0) = pk;
        }
      }
    }
  }
}

// ---------------- flash attention (GQA, KVBLK=128, 16 waves = 4 heads x 4 kj-quarters) ----------------
// grid (B*KVH=8, L/32=64), 1024 threads. Wave (h,kq): head h, kj-quarter kq (32 kj of the
// 128-kj tile). Per wave per round: 8 b128 LDS reads, 8 MFMA32, 16 exp  (== R9's lean
// profile) but HALF the barrier rounds (16) and 2x the waves/CU. T14 reg-staging,
// counted raw barriers, max-free softmax, in-register P. Quarter partials merged via
// a 2-round pairwise tree through the dead staging LDS.
__global__ __launch_bounds__(1024, 8) void k_attn(const unsigned short* __restrict__ q_ws,
                                                  const unsigned short* __restrict__ k_ws,
                                                  const unsigned short* __restrict__ vt_ws,
                                                  const float* __restrict__ mask,
                                                  const unsigned char* __restrict__ mflags,
                                                  unsigned short* __restrict__ ctx) {
  const int bk = blockIdx.x;            // b*4 + kvh (== XCD id -> L2 locality)
  const int qt = blockIdx.y;            // 32-row q tile
  const int b = bk >> 2, kvh = bk & 3;
  const int t = threadIdx.x;            // 0..1023
  const int wid = t >> 6, lane = t & 63;
  const int l31 = lane & 31, g1 = lane >> 5;
  const int h = wid & 3, kq = wid >> 2; // head, kj-quarter

  __shared__ unsigned short smem[32768];   // 64KB: 2 bufs x [K 16KB | V 16KB]
  __shared__ float lred[4][4][64];         // [kq][h][lane] l partials

  const int qrow = qt * 32 + l31;

  // ---- Q frags: B-operand 32x32x16: n=q=l31, k=d = ks*16 + g1*8 + j ----
  const unsigned short* qbase = q_ws + ((size_t)b * L_ + qrow) * H_ +
                                (kvh * 4 + h) * 64 + g1 * 8;
  short8 qf[4];
#pragma unroll
  for (int ks = 0; ks < 4; ++ks) qf[ks] = *(const short8*)(qbase + ks * 16);

  // ---- mask flags -> register bitmask (32 bits = 32 x 64-kj blocks) ----
  const unsigned int* fp = (const unsigned int*)(mflags + b * 1024 + (qt >> 1) * 32);
  unsigned int fm = 0;
#pragma unroll
  for (int w = 0; w < 8; ++w) {
    unsigned int wv = fp[w];
    fm |= ((wv & 0x000000FFu) ? 1u : 0u) << (w * 4 + 0);
    fm |= ((wv & 0x0000FF00u) ? 1u : 0u) << (w * 4 + 1);
    fm |= ((wv & 0x00FF0000u) ? 1u : 0u) << (w * 4 + 2);
    fm |= ((wv & 0xFF000000u) ? 1u : 0u) << (w * 4 + 3);
  }
  fm = __builtin_amdgcn_readfirstlane(fm);

  // ---- staging (pre-swizzled sources, rule #21) ----
  // K tile 128x64: slot t -> row t>>3, gran t&7 ; src col gran = (t&7)^(row&7)
  // V tile 64x128: slot t -> row t>>4, gran t&15; src col gran = (t&15)^(row&15)
  const int krow = t >> 3, kgr = t & 7;
  const int vrow = t >> 4, vgr = t & 15;
  const unsigned short* ksrc = k_ws + ((size_t)b * L_ + krow) * 256 + kvh * 64 +
                               ((kgr ^ (krow & 7)) * 8);
  const unsigned short* vsrc = vt_ws + ((size_t)(b * KVH_ + kvh) * 64 + vrow) * 2048 +
                               ((vgr ^ (vrow & 15)) * 8);

  const f32x16 z16 = {0,0,0,0,0,0,0,0,0,0,0,0,0,0,0,0};
  f32x16 o_[2];                           // [db] : O^T[d=db*32+row][q=l31] (kj-quarter partial)
  o_[0] = z16; o_[1] = z16;
  float l_part = 0.f;

  const int rK = kq * 32 + l31, swK = rK & 7;
  const int swV = l31 & 15;

  short8 kst, vst;                        // staged regs (next tile)
#define LOADR(kt) { kst = *(const short8*)(ksrc + (size_t)(kt) * 32768); \
                    vst = *(const short8*)(vsrc + (kt) * 128); }
#define WRITES(buf) { unsigned short* dk = smem + (buf) * 16384;         \
                      *(short8*)(dk + t * 8) = kst;                      \
                      *(short8*)(dk + 8192 + t * 8) = vst; }

  LOADR(0);
  WRITES(0);
  LOADR(1);
  __syncthreads();                        // full drain once; invariant established

#pragma unroll 1
  for (int kt = 0; kt < 16; ++kt) {
    const int cur = kt & 1;
    const unsigned short* lk = smem + cur * 16384;
    const unsigned short* lv = lk + 8192;

    // ---- frags of tile kt (wave's 32-kj quarter) ----
    short8 kf[4];
#pragma unroll
    for (int ks = 0; ks < 4; ++ks)
      kf[ks] = *(const short8*)&lk[rK * 64 + (((ks * 2 + g1) ^ swK) * 8)];
    short8 vf[2][2];
#pragma unroll
    for (int db = 0; db < 2; ++db)
#pragma unroll
      for (int s = 0; s < 2; ++s)
        vf[db][s] = *(const short8*)&lv[(db * 32 + l31) * 128 +
                                        (((kq * 4 + s * 2 + g1) ^ swV) * 8)];

    // ---- T14: regs(kt+1) landed (issued a full iter ago) -> write-late, issue kt+2
    asm volatile("s_waitcnt vmcnt(0)" ::: "memory");
    if (kt + 1 < 16) WRITES(cur ^ 1);
    if (kt + 2 < 16) LOADR(kt + 2);

    // ---- S^T[32kj x 32q] = K * Q^T ----
    f32x16 sv = z16;
    __builtin_amdgcn_s_setprio(1);
#pragma unroll
    for (int ks = 0; ks < 4; ++ks) sv = MFMA32(kf[ks], qf[ks], sv, 0, 0, 0);
    __builtin_amdgcn_s_setprio(0);

    if (fm & (1u << (2 * kt + (kq >> 1)))) {   // rare: mask 64-kj block nonzero
      const float* mrow = mask + ((size_t)b * L_ + qrow) * L_ + kt * 128 + kq * 32 + g1 * 4;
#pragma unroll
      for (int rg = 0; rg < 4; ++rg) {
        float4 mv = *(const float4*)(mrow + rg * 8);
#pragma unroll
        for (int j = 0; j < 4; ++j) sv[rg * 4 + j] = fmaf((&mv.x)[j], LOG2E, sv[rg * 4 + j]);
      }
    }

    // ---- max-free softmax + in-register P re-layout (cvt_pk + permlane32_swap) ----
    float e[16];
#pragma unroll
    for (int r = 0; r < 16; ++r) e[r] = EXP2(sv[r]);
    l_part += (((e[0] + e[1]) + (e[2] + e[3])) + ((e[4] + e[5]) + (e[6] + e[7]))) +
              (((e[8] + e[9]) + (e[10] + e[11])) + ((e[12] + e[13]) + (e[14] + e[15])));
    unsigned int w0 = cvtpk(e[0], e[1]),   w1 = cvtpk(e[2], e[3]);
    unsigned int w2 = cvtpk(e[4], e[5]),   w3 = cvtpk(e[6], e[7]);
    unsigned int w4 = cvtpk(e[8], e[9]),   w5 = cvtpk(e[10], e[11]);
    unsigned int w6 = cvtpk(e[12], e[13]), w7 = cvtpk(e[14], e[15]);
    plswap(w0, w2); plswap(w1, w3);        // kstep 0 (kj_local 0..15)
    plswap(w4, w6); plswap(w5, w7);        // kstep 1 (kj_local 16..31)
    short8 pa0 = mk8(w0, w1, w2, w3);
    short8 pa1 = mk8(w4, w5, w6, w7);

    // ---- PV: O^T[d][q] += V^T * P^T ----
    __builtin_amdgcn_s_setprio(1);
#pragma unroll
    for (int db = 0; db < 2; ++db) {
      o_[db] = MFMA32(vf[db][0], pa0, o_[db], 0, 0, 0);
      o_[db] = MFMA32(vf[db][1], pa1, o_[db], 0, 0, 0);
    }
    __builtin_amdgcn_s_setprio(0);

    // ---- raw barrier: ds_writes visible; kt+2 global loads stay in flight ----
    asm volatile("s_waitcnt lgkmcnt(0)" ::: "memory");
    __builtin_amdgcn_s_barrier();
    __builtin_amdgcn_sched_barrier(0);
  }
#undef LOADR
#undef WRITES

  // ---- epilogue: pairwise-tree merge of 4 kj-quarter partials via dead staging LDS ----
  float lt = l_part + __shfl_xor(l_part, 32);
  float* red = (float*)smem;              // 16384 floats; region = 8192 floats (32KB)
  lred[kq][h][lane] = lt;

  if (kq >= 2) {                          // round 1 writers: kq2 -> region 0, kq3 -> region 1
    float* rg = red + (kq - 2) * 8192 + h * 2048;
#pragma unroll
    for (int db = 0; db < 2; ++db)
#pragma unroll
      for (int w4 = 0; w4 < 4; ++w4) {
        f32x4 pv = { o_[db][w4 * 4 + 0], o_[db][w4 * 4 + 1],
                     o_[db][w4 * 4 + 2], o_[db][w4 * 4 + 3] };
        *(f32x4*)&rg[(db * 4 + w4) * 256 + lane * 4] = pv;
      }
  }
  __syncthreads();
  if (kq < 2) {                           // kq0 += kq2 ; kq1 += kq3
    const float* rg = red + kq * 8192 + h * 2048;
#pragma unroll
    for (int db = 0; db < 2; ++db)
#pragma unroll
      for (int w4 = 0; w4 < 4; ++w4) {
        f32x4 pv = *(const f32x4*)&rg[(db * 4 + w4) * 256 + lane * 4];
#pragma unroll
        for (int j = 0; j < 4; ++j) o_[db][w4 * 4 + j] += pv[j];
      }
    lt += lred[kq + 2][h][lane];
  }
  __syncthreads();
  if (kq == 1) {                          // round 2 writer: kq1 -> region 0
    float* rg = red + h * 2048;
#pragma unroll
    for (int db = 0; db < 2; ++db)
#pragma unroll
      for (int w4 = 0; w4 < 4; ++w4) {
        f32x4 pv = { o_[db][w4 * 4 + 0], o_[db][w4 * 4 + 1],
                     o_[db][w4 * 4 + 2], o_[db][w4 * 4 + 3] };
        *(f32x4*)&rg[(db * 4 + w4) * 256 + lane * 4] = pv;
      }
    lred[1][h][lane] = lt;
  }
  __syncthreads();
  if (kq == 0) {                          // final: kq0 += kq1(+kq3), normalize, store
    const float* rg = red + h * 2048;
    lt += lred[1][h][lane];
    const float inv = 1.f / lt;
#pragma unroll
    for (int db = 0; db < 2; ++db) {
      f32x16 acc = o_[db];
#pragma unroll
      for (int w4 = 0; w4 < 4; ++w4) {
        f32x4 pv = *(const f32x4*)&rg[(db * 4 + w4) * 256 + lane * 4];
#pragma unroll
        for (int j = 0; j < 4; ++j) acc[w4 * 4 + j] += pv[j];
      }
      unsigned short* cp = ctx + ((size_t)b * L_ + qrow) * H_ +
                           (kvh * 4 + h) * 64 + db * 32 + g1 * 4;
#pragma unroll
      for (int k4 = 0; k4 < 4; ++k4) {
        unsigned int a0 = cvtpk(acc[4 * k4 + 0] * inv, acc[4 * k4 + 1] * inv);
        unsigned int a1 = cvtpk(acc[4 * k4 + 2] * inv, acc[4 * k4 + 3] * inv);
        *(unsigned int*)(cp + 8 * k4) = a0;
        *(unsigned int*)(cp + 8 * k4 + 2) = a1;
      }
    }
  }
}

// ---------------- launch ----------------
extern "C" void kernel_launch(void* const* d_in, const int* in_sizes, int n_in,
                              void* d_out, int out_size, void* d_ws, size_t ws_size,
                              hipStream_t stream) {
  const float* x    = (const float*)d_in[0];
  const float* mask = (const float*)d_in[1];
  const float* Wq   = (const float*)d_in[2];
  const float* bq   = (const float*)d_in[3];
  const float* Wk   = (const float*)d_in[4];
  const float* bk   = (const float*)d_in[5];
  const float* Wv   = (const float*)d_in[6];
  const float* bv   = (const float*)d_in[7];
  const float* Wo   = (const float*)d_in[8];
  const float* bo   = (const float*)d_in[9];
  float* out = (float*)d_out;

  char* ws = (char*)d_ws;
  unsigned short* xb    = (unsigned short*)(ws);                 // 8 MB (reused as ctx)
  unsigned short* ctx   = xb;
  unsigned short* wcat  = (unsigned short*)(ws + 8388608);       // 3 MB
  unsigned short* wo_b  = (unsigned short*)(ws + 11534336);      // 2 MB
  unsigned short* q_ws  = (unsigned short*)(ws + 13631488);      // 8 MB
  unsigned short* k_ws  = (unsigned short*)(ws + 22020096);      // 2 MB
  unsigned short* vt_ws = (unsigned short*)(ws + 24117248);      // 2 MB
  unsigned char*  mflg  = (unsigned char*)(ws + 26214400);       // 2 KB

  k_prep<<<dim3(8704), dim3(256), 0, stream>>>(x, Wq, Wk, Wv, Wo, mask, xb, wcat, wo_b, mflg);
  k_gemm<0><<<dim3(12, 32), dim3(256), 0, stream>>>(xb, wcat, bq, bk, bv, q_ws, k_ws, vt_ws, nullptr);
  k_attn<<<dim3(8, 64), dim3(1024), 0, stream>>>(q_ws, k_ws, vt_ws, mask, mflg, ctx);
  k_gemm<1><<<dim3(8, 32), dim3(256), 0, stream>>>(ctx, wo_b, bo, nullptr, nullptr,
                                                   nullptr, nullptr, nullptr, out);
}

// Round 12
// 109.967 us; speedup vs baseline: 5.6088x; 5.6088x over previous
//
#include <hip/hip_runtime.h>

#define B_   2
#define L_   2048
#define H_   1024
#define NH_  16
#define KVH_ 4
#define HD_  64

typedef short short8 __attribute__((ext_vector_type(8)));
typedef float f32x4 __attribute__((ext_vector_type(4)));
typedef float f32x16 __attribute__((ext_vector_type(16)));
typedef unsigned short u16x4 __attribute__((ext_vector_type(4)));

#define LOG2E 1.4426950408889634f
#define QSC   0.18033688011112042f   /* 0.125 * log2(e) */
#define MFMA   __builtin_amdgcn_mfma_f32_16x16x32_bf16
#define MFMA32 __builtin_amdgcn_mfma_f32_32x32x16_bf16

#if __has_builtin(__builtin_amdgcn_exp2f)
#define EXP2(x) __builtin_amdgcn_exp2f(x)
#else
#define EXP2(x) exp2f(x)
#endif

static __device__ __forceinline__ unsigned short f2bf(float f) {
  unsigned int u = __float_as_uint(f);
  u += 0x7FFFu + ((u >> 16) & 1u);
  return (unsigned short)(u >> 16);
}

static __device__ __forceinline__ unsigned int cvtpk(float lo, float hi) {
  unsigned int r;
  asm("v_cvt_pk_bf16_f32 %0, %1, %2" : "=v"(r) : "v"(lo), "v"(hi));
  return r;
}

// dst' = {dst.lo32lanes, src.lo32lanes}, src' = {dst.hi32lanes, src.hi32lanes}
static __device__ __forceinline__ void plswap(unsigned int& a, unsigned int& b) {
  asm("v_permlane32_swap_b32 %0, %1" : "+v"(a), "+v"(b));
}

static __device__ __forceinline__ short8 mk8(unsigned int w0, unsigned int w1,
                                             unsigned int w2, unsigned int w3) {
  union { unsigned int u[4]; short8 s; } x;
  x.u[0] = w0; x.u[1] = w1; x.u[2] = w2; x.u[3] = w3;
  return x.s;
}

static __device__ __forceinline__ void gload_lds16(const void* g, void* l) {
  __builtin_amdgcn_global_load_lds(
      (const __attribute__((address_space(1))) unsigned int*)g,
      (__attribute__((address_space(3))) unsigned int*)l, 16, 0, 0);
}

// ---------------- merged prep: convert x, convert weights, mask scan ----------------
__global__ __launch_bounds__(256) void k_prep(const float* __restrict__ x,
                                              const float* __restrict__ Wq,
                                              const float* __restrict__ Wk,
                                              const float* __restrict__ Wv,
                                              const float* __restrict__ Wo,
                                              const float* __restrict__ mask,
                                              unsigned short* __restrict__ xb,
                                              unsigned short* __restrict__ wcat,
                                              unsigned short* __restrict__ wo_b,
                                              unsigned char* __restrict__ flags) {
  const int blk = blockIdx.x;
  const int t = threadIdx.x;
  if (blk < 4096) {                       // ---- convert x ----
    size_t i = ((size_t)blk * 256 + t) * 4;
    float4 v = *(const float4*)(x + i);
    u16x4 o = { f2bf(v.x), f2bf(v.y), f2bf(v.z), f2bf(v.w) };
    *(u16x4*)(xb + i) = o;
  } else if (blk < 6656) {                // ---- convert weights ----
    int r = blk - 4096;
    int c = t * 4;
    const float* src;
    unsigned short* dst;
    if (r < 1024)      { src = Wq + (size_t)r * 1024;          dst = wcat + (size_t)r * 1024; }
    else if (r < 1280) { src = Wk + (size_t)(r - 1024) * 1024; dst = wcat + (size_t)r * 1024; }
    else if (r < 1536) { src = Wv + (size_t)(r - 1280) * 1024; dst = wcat + (size_t)r * 1024; }
    else               { src = Wo + (size_t)(r - 1536) * 1024; dst = wo_b + (size_t)(r - 1536) * 1024; }
    float4 v = *(const float4*)(src + c);
    u16x4 o = { f2bf(v.x), f2bf(v.y), f2bf(v.z), f2bf(v.w) };
    *(u16x4*)(dst + c) = o;
  } else {                                // ---- mask block-zero scan ----
    const int mb = blk - 6656;            // b*1024 + qb*32 + kb
    const int b = mb >> 10, qb = (mb >> 5) & 31, kb = mb & 31;
    const float* base = mask + ((size_t)b * L_ + qb * 64) * L_ + kb * 64;
    const int r0 = t >> 4, c = (t & 15) * 4;
    bool nz = false;
#pragma unroll
    for (int i = 0; i < 4; ++i) {
      float4 v = *(const float4*)(base + (size_t)(r0 + i * 16) * L_ + c);
      nz |= (v.x != 0.f) | (v.y != 0.f) | (v.z != 0.f) | (v.w != 0.f);
    }
    __shared__ int anyv;
    if (t == 0) anyv = 0;
    __syncthreads();
    if (__any(nz) && (t & 63) == 0) atomicOr(&anyv, 1);
    __syncthreads();
    if (t == 0) flags[mb] = (unsigned char)anyv;
  }
}

// ---------------- GEMM (128x128, BK=64, XOR-swizzle, 2-phase dbuf pipeline) ----------------
template <int MODE>
__global__ __launch_bounds__(256) void k_gemm(const unsigned short* __restrict__ A,
                                              const unsigned short* __restrict__ Bt,
                                              const float* __restrict__ bias0,
                                              const float* __restrict__ bias1,
                                              const float* __restrict__ bias2,
                                              unsigned short* __restrict__ q_ws,
                                              unsigned short* __restrict__ k_ws,
                                              unsigned short* __restrict__ vt_ws,
                                              float* __restrict__ outp) {
  const int bn = blockIdx.x, bm = blockIdx.y;
  const int t = threadIdx.x;
  const int lane = t & 63, li = lane & 15, g = lane >> 4;
  const int wid = t >> 6, wr = wid >> 1, wc = wid & 1;
  __shared__ unsigned short lds_a[2][128 * 64];   // [buf][row][slot], slot s holds G col s^(row&7)
  __shared__ unsigned short lds_b[2][128 * 64];

  const f32x4 z = {0.f, 0.f, 0.f, 0.f};
  f32x4 acc[4][4];
#pragma unroll
  for (int m = 0; m < 4; ++m)
#pragma unroll
    for (int n = 0; n < 4; ++n) acc[m][n] = z;

  // staging: 4 chunks of 256 threads cover 1024 granule-slots (128 rows x 8 slots)
  const unsigned short* asrc[4];
  const unsigned short* bsrc[4];
  int ldst[4];
#pragma unroll
  for (int c = 0; c < 4; ++c) {
    const int idx = c * 256 + t, row = idx >> 3, sl = idx & 7;
    const int gcol = (sl ^ (row & 7)) * 8;
    asrc[c] = A  + (size_t)(bm * 128 + row) * 1024 + gcol;
    bsrc[c] = Bt + (size_t)(bn * 128 + row) * 1024 + gcol;
    ldst[c] = idx * 8;
  }
  const int rs = li & 7;

#define GSTAGE(buf, kc)                                                  \
  {                                                                      \
    _Pragma("unroll")                                                    \
    for (int c = 0; c < 4; ++c) {                                        \
      gload_lds16(asrc[c] + (kc), &lds_a[buf][ldst[c]]);                 \
      gload_lds16(bsrc[c] + (kc), &lds_b[buf][ldst[c]]);                 \
    }                                                                    \
  }

  GSTAGE(0, 0);
  __syncthreads();                        // buf0 ready

#pragma unroll 1
  for (int it = 0; it < 16; ++it) {
    const int cur = it & 1;
    if (it + 1 < 16) GSTAGE(cur ^ 1, (it + 1) * 64);   // issue next tile first (T3-min)
#pragma unroll
    for (int ks = 0; ks < 2; ++ks) {
      short8 af[4], bf[4];
#pragma unroll
      for (int m = 0; m < 4; ++m)
        af[m] = *(const short8*)&lds_a[cur][(wr * 64 + m * 16 + li) * 64 + (((ks * 4 + g) ^ rs) * 8)];
#pragma unroll
      for (int n = 0; n < 4; ++n)
        bf[n] = *(const short8*)&lds_b[cur][(wc * 64 + n * 16 + li) * 64 + (((ks * 4 + g) ^ rs) * 8)];
#pragma unroll
      for (int m = 0; m < 4; ++m)
#pragma unroll
        for (int n = 0; n < 4; ++n)
          acc[m][n] = MFMA(af[m], bf[n], acc[m][n], 0, 0, 0);
    }
    __syncthreads();    // drains this iter's GSTAGE (vmcnt) + all reads of cur (lgkm)
  }
#undef GSTAGE

#pragma unroll
  for (int m = 0; m < 4; ++m) {
    const int row0 = bm * 128 + wr * 64 + m * 16 + 4 * g;
#pragma unroll
    for (int n = 0; n < 4; ++n) {
      const int col = bn * 128 + wc * 64 + n * 16 + li;
      f32x4 v = acc[m][n];
      if (MODE == 1) {
        const float bias = bias0[col];
#pragma unroll
        for (int r = 0; r < 4; ++r) outp[(size_t)(row0 + r) * 1024 + col] = v[r] + bias;
      } else {
        if (col < 1024) {
          const float bias = bias0[col];
#pragma unroll
          for (int r = 0; r < 4; ++r) q_ws[(size_t)(row0 + r) * 1024 + col] = f2bf((v[r] + bias) * QSC);
        } else if (col < 1280) {
          const int cc = col - 1024;
          const float bias = bias1[cc];
#pragma unroll
          for (int r = 0; r < 4; ++r) k_ws[(size_t)(row0 + r) * 256 + cc] = f2bf(v[r] + bias);
        } else {
          const int cc = col - 1280;
          const float bias = bias2[cc];
          const int kvh = cc >> 6, d = cc & 63;
          const int b = row0 >> 11, l0 = row0 & 2047;
          u16x4 pk = { f2bf(v[0] + bias), f2bf(v[1] + bias), f2bf(v[2] + bias), f2bf(v[3] + bias) };
          *(u16x4*)(vt_ws + ((size_t)((b * KVH_ + kvh) * 64 + d)) * 2048 + l0) = pk;
        }
      }
    }
  }
}

// ---------------- flash attention (GQA, KVBLK=128, 16 waves = 4 heads x 4 kj-quarters) ----------------
// grid (B*KVH=8, L/32=64), 1024 threads, __launch_bounds__(1024,4): VGPR cap 128 (R11's
// cap-64 spilled the accumulators -> 2.7GB scratch traffic; this is the corrected A/B).
// Per wave per round: 8 b128 LDS reads, 8 MFMA32, 16 exp2 (R9's lean profile), but 16
// barrier rounds instead of 32. T14 reg-staging, counted raw barriers, max-free softmax,
// in-register P (cvt_pk + permlane32_swap). Quarter partials merged via 2-round tree.
__global__ __launch_bounds__(1024, 4) void k_attn(const unsigned short* __restrict__ q_ws,
                                                  const unsigned short* __restrict__ k_ws,
                                                  const unsigned short* __restrict__ vt_ws,
                                                  const float* __restrict__ mask,
                                                  const unsigned char* __restrict__ mflags,
                                                  unsigned short* __restrict__ ctx) {
  const int bk = blockIdx.x;            // b*4 + kvh (== XCD id -> L2 locality)
  const int qt = blockIdx.y;            // 32-row q tile
  const int b = bk >> 2, kvh = bk & 3;
  const int t = threadIdx.x;            // 0..1023
  const int wid = t >> 6, lane = t & 63;
  const int l31 = lane & 31, g1 = lane >> 5;
  const int h = wid & 3, kq = wid >> 2; // head, kj-quarter

  __shared__ unsigned short smem[32768];   // 64KB: 2 bufs x [K 16KB | V 16KB]
  __shared__ float lred[4][4][64];         // [kq][h][lane] l partials

  const int qrow = qt * 32 + l31;

  // ---- Q frags: B-operand 32x32x16: n=q=l31, k=d = ks*16 + g1*8 + j ----
  const unsigned short* qbase = q_ws + ((size_t)b * L_ + qrow) * H_ +
                                (kvh * 4 + h) * 64 + g1 * 8;
  short8 qf[4];
#pragma unroll
  for (int ks = 0; ks < 4; ++ks) qf[ks] = *(const short8*)(qbase + ks * 16);

  // ---- mask flags -> register bitmask (32 bits = 32 x 64-kj blocks) ----
  const unsigned int* fp = (const unsigned int*)(mflags + b * 1024 + (qt >> 1) * 32);
  unsigned int fm = 0;
#pragma unroll
  for (int w = 0; w < 8; ++w) {
    unsigned int wv = fp[w];
    fm |= ((wv & 0x000000FFu) ? 1u : 0u) << (w * 4 + 0);
    fm |= ((wv & 0x0000FF00u) ? 1u : 0u) << (w * 4 + 1);
    fm |= ((wv & 0x00FF0000u) ? 1u : 0u) << (w * 4 + 2);
    fm |= ((wv & 0xFF000000u) ? 1u : 0u) << (w * 4 + 3);
  }
  fm = __builtin_amdgcn_readfirstlane(fm);

  // ---- staging (pre-swizzled sources, rule #21) ----
  // K tile 128x64: slot t -> row t>>3, gran t&7 ; src col gran = (t&7)^(row&7)
  // V tile 64x128: slot t -> row t>>4, gran t&15; src col gran = (t&15)^(row&15)
  const int krow = t >> 3, kgr = t & 7;
  const int vrow = t >> 4, vgr = t & 15;
  const unsigned short* ksrc = k_ws + ((size_t)b * L_ + krow) * 256 + kvh * 64 +
                               ((kgr ^ (krow & 7)) * 8);
  const unsigned short* vsrc = vt_ws + ((size_t)(b * KVH_ + kvh) * 64 + vrow) * 2048 +
                               ((vgr ^ (vrow & 15)) * 8);

  const f32x16 z16 = {0,0,0,0,0,0,0,0,0,0,0,0,0,0,0,0};
  f32x16 o_[2];                           // [db] : O^T[d=db*32+row][q=l31] (kj-quarter partial)
  o_[0] = z16; o_[1] = z16;
  float l_part = 0.f;

  const int rK = kq * 32 + l31, swK = rK & 7;
  const int swV = l31 & 15;

  short8 kst, vst;                        // staged regs (next tile)
#define LOADR(kt) { kst = *(const short8*)(ksrc + (size_t)(kt) * 32768); \
                    vst = *(const short8*)(vsrc + (kt) * 128); }
#define WRITES(buf) { unsigned short* dk = smem + (buf) * 16384;         \
                      *(short8*)(dk + t * 8) = kst;                      \
                      *(short8*)(dk + 8192 + t * 8) = vst; }

  LOADR(0);
  WRITES(0);
  LOADR(1);
  __syncthreads();                        // full drain once; invariant established

#pragma unroll 1
  for (int kt = 0; kt < 16; ++kt) {
    const int cur = kt & 1;
    const unsigned short* lk = smem + cur * 16384;
    const unsigned short* lv = lk + 8192;

    // ---- frags of tile kt (wave's 32-kj quarter) ----
    short8 kf[4];
#pragma unroll
    for (int ks = 0; ks < 4; ++ks)
      kf[ks] = *(const short8*)&lk[rK * 64 + (((ks * 2 + g1) ^ swK) * 8)];
    short8 vf[2][2];
#pragma unroll
    for (int db = 0; db < 2; ++db)
#pragma unroll
      for (int s = 0; s < 2; ++s)
        vf[db][s] = *(const short8*)&lv[(db * 32 + l31) * 128 +
                                        (((kq * 4 + s * 2 + g1) ^ swV) * 8)];

    // ---- T14: regs(kt+1) landed (issued a full iter ago) -> write-late, issue kt+2
    asm volatile("s_waitcnt vmcnt(0)" ::: "memory");
    if (kt + 1 < 16) WRITES(cur ^ 1);
    if (kt + 2 < 16) LOADR(kt + 2);

    // ---- S^T[32kj x 32q] = K * Q^T ----
    f32x16 sv = z16;
    __builtin_amdgcn_s_setprio(1);
#pragma unroll
    for (int ks = 0; ks < 4; ++ks) sv = MFMA32(kf[ks], qf[ks], sv, 0, 0, 0);
    __builtin_amdgcn_s_setprio(0);

    if (fm & (1u << (2 * kt + (kq >> 1)))) {   // rare: mask 64-kj block nonzero
      const float* mrow = mask + ((size_t)b * L_ + qrow) * L_ + kt * 128 + kq * 32 + g1 * 4;
#pragma unroll
      for (int rg = 0; rg < 4; ++rg) {
        float4 mv = *(const float4*)(mrow + rg * 8);
#pragma unroll
        for (int j = 0; j < 4; ++j) sv[rg * 4 + j] = fmaf((&mv.x)[j], LOG2E, sv[rg * 4 + j]);
      }
    }

    // ---- max-free softmax + in-register P re-layout (cvt_pk + permlane32_swap) ----
    float e[16];
#pragma unroll
    for (int r = 0; r < 16; ++r) e[r] = EXP2(sv[r]);
    l_part += (((e[0] + e[1]) + (e[2] + e[3])) + ((e[4] + e[5]) + (e[6] + e[7]))) +
              (((e[8] + e[9]) + (e[10] + e[11])) + ((e[12] + e[13]) + (e[14] + e[15])));
    unsigned int w0 = cvtpk(e[0], e[1]),   w1 = cvtpk(e[2], e[3]);
    unsigned int w2 = cvtpk(e[4], e[5]),   w3 = cvtpk(e[6], e[7]);
    unsigned int w4 = cvtpk(e[8], e[9]),   w5 = cvtpk(e[10], e[11]);
    unsigned int w6 = cvtpk(e[12], e[13]), w7 = cvtpk(e[14], e[15]);
    plswap(w0, w2); plswap(w1, w3);        // kstep 0 (kj_local 0..15)
    plswap(w4, w6); plswap(w5, w7);        // kstep 1 (kj_local 16..31)
    short8 pa0 = mk8(w0, w1, w2, w3);
    short8 pa1 = mk8(w4, w5, w6, w7);

    // ---- PV: O^T[d][q] += V^T * P^T ----
    __builtin_amdgcn_s_setprio(1);
#pragma unroll
    for (int db = 0; db < 2; ++db) {
      o_[db] = MFMA32(vf[db][0], pa0, o_[db], 0, 0, 0);
      o_[db] = MFMA32(vf[db][1], pa1, o_[db], 0, 0, 0);
    }
    __builtin_amdgcn_s_setprio(0);

    // ---- raw barrier: ds_writes visible; kt+2 global loads stay in flight ----
    asm volatile("s_waitcnt lgkmcnt(0)" ::: "memory");
    __builtin_amdgcn_s_barrier();
    __builtin_amdgcn_sched_barrier(0);
  }
#undef LOADR
#undef WRITES

  // ---- epilogue: pairwise-tree merge of 4 kj-quarter partials via dead staging LDS ----
  float lt = l_part + __shfl_xor(l_part, 32);
  float* red = (float*)smem;              // 16384 floats; region = 8192 floats (32KB)
  lred[kq][h][lane] = lt;

  if (kq >= 2) {                          // round 1 writers: kq2 -> region 0, kq3 -> region 1
    float* rg = red + (kq - 2) * 8192 + h * 2048;
#pragma unroll
    for (int db = 0; db < 2; ++db)
#pragma unroll
      for (int w4 = 0; w4 < 4; ++w4) {
        f32x4 pv = { o_[db][w4 * 4 + 0], o_[db][w4 * 4 + 1],
                     o_[db][w4 * 4 + 2], o_[db][w4 * 4 + 3] };
        *(f32x4*)&rg[(db * 4 + w4) * 256 + lane * 4] = pv;
      }
  }
  __syncthreads();
  if (kq < 2) {                           // kq0 += kq2 ; kq1 += kq3
    const float* rg = red + kq * 8192 + h * 2048;
#pragma unroll
    for (int db = 0; db < 2; ++db)
#pragma unroll
      for (int w4 = 0; w4 < 4; ++w4) {
        f32x4 pv = *(const f32x4*)&rg[(db * 4 + w4) * 256 + lane * 4];
#pragma unroll
        for (int j = 0; j < 4; ++j) o_[db][w4 * 4 + j] += pv[j];
      }
    lt += lred[kq + 2][h][lane];
  }
  __syncthreads();
  if (kq == 1) {                          // round 2 writer: kq1 -> region 0
    float* rg = red + h * 2048;
#pragma unroll
    for (int db = 0; db < 2; ++db)
#pragma unroll
      for (int w4 = 0; w4 < 4; ++w4) {
        f32x4 pv = { o_[db][w4 * 4 + 0], o_[db][w4 * 4 + 1],
                     o_[db][w4 * 4 + 2], o_[db][w4 * 4 + 3] };
        *(f32x4*)&rg[(db * 4 + w4) * 256 + lane * 4] = pv;
      }
    lred[1][h][lane] = lt;
  }
  __syncthreads();
  if (kq == 0) {                          // final: kq0 += kq1(+kq3), normalize, store
    const float* rg = red + h * 2048;
    lt += lred[1][h][lane];
    const float inv = 1.f / lt;
#pragma unroll
    for (int db = 0; db < 2; ++db) {
      f32x16 acc = o_[db];
#pragma unroll
      for (int w4 = 0; w4 < 4; ++w4) {
        f32x4 pv = *(const f32x4*)&rg[(db * 4 + w4) * 256 + lane * 4];
#pragma unroll
        for (int j = 0; j < 4; ++j) acc[w4 * 4 + j] += pv[j];
      }
      unsigned short* cp = ctx + ((size_t)b * L_ + qrow) * H_ +
                           (kvh * 4 + h) * 64 + db * 32 + g1 * 4;
#pragma unroll
      for (int k4 = 0; k4 < 4; ++k4) {
        unsigned int a0 = cvtpk(acc[4 * k4 + 0] * inv, acc[4 * k4 + 1] * inv);
        unsigned int a1 = cvtpk(acc[4 * k4 + 2] * inv, acc[4 * k4 + 3] * inv);
        *(unsigned int*)(cp + 8 * k4) = a0;
        *(unsigned int*)(cp + 8 * k4 + 2) = a1;
      }
    }
  }
}

// ---------------- launch ----------------
extern "C" void kernel_launch(void* const* d_in, const int* in_sizes, int n_in,
                              void* d_out, int out_size, void* d_ws, size_t ws_size,
                              hipStream_t stream) {
  const float* x    = (const float*)d_in[0];
  const float* mask = (const float*)d_in[1];
  const float* Wq   = (const float*)d_in[2];
  const float* bq   = (const float*)d_in[3];
  const float* Wk   = (const float*)d_in[4];
  const float* bk   = (const float*)d_in[5];
  const float* Wv   = (const float*)d_in[6];
  const float* bv   = (const float*)d_in[7];
  const float* Wo   = (const float*)d_in[8];
  const float* bo   = (const float*)d_in[9];
  float* out = (float*)d_out;

  char* ws = (char*)d_ws;
  unsigned short* xb    = (unsigned short*)(ws);                 // 8 MB (reused as ctx)
  unsigned short* ctx   = xb;
  unsigned short* wcat  = (unsigned short*)(ws + 8388608);       // 3 MB
  unsigned short* wo_b  = (unsigned short*)(ws + 11534336);      // 2 MB
  unsigned short* q_ws  = (unsigned short*)(ws + 13631488);      // 8 MB
  unsigned short* k_ws  = (unsigned short*)(ws + 22020096);      // 2 MB
  unsigned short* vt_ws = (unsigned short*)(ws + 24117248);      // 2 MB
  unsigned char*  mflg  = (unsigned char*)(ws + 26214400);       // 2 KB

  k_prep<<<dim3(8704), dim3(256), 0, stream>>>(x, Wq, Wk, Wv, Wo, mask, xb, wcat, wo_b, mflg);
  k_gemm<0><<<dim3(12, 32), dim3(256), 0, stream>>>(xb, wcat, bq, bk, bv, q_ws, k_ws, vt_ws, nullptr);
  k_attn<<<dim3(8, 64), dim3(1024), 0, stream>>>(q_ws, k_ws, vt_ws, mask, mflg, ctx);
  k_gemm<1><<<dim3(8, 32), dim3(256), 0, stream>>>(ctx, wo_b, bo, nullptr, nullptr,
                                                   nullptr, nullptr, nullptr, out);
}

// Round 13
// 105.583 us; speedup vs baseline: 5.8416x; 1.0415x over previous
//
#include <hip/hip_runtime.h>

#define B_   2
#define L_   2048
#define H_   1024
#define NH_  16
#define KVH_ 4
#define HD_  64

typedef short short8 __attribute__((ext_vector_type(8)));
typedef float f32x4 __attribute__((ext_vector_type(4)));
typedef float f32x16 __attribute__((ext_vector_type(16)));
typedef unsigned short u16x4 __attribute__((ext_vector_type(4)));

#define LOG2E 1.4426950408889634f
#define QSC   0.18033688011112042f   /* 0.125 * log2(e) */
#define MFMA   __builtin_amdgcn_mfma_f32_16x16x32_bf16
#define MFMA32 __builtin_amdgcn_mfma_f32_32x32x16_bf16

#if __has_builtin(__builtin_amdgcn_exp2f)
#define EXP2(x) __builtin_amdgcn_exp2f(x)
#else
#define EXP2(x) exp2f(x)
#endif

static __device__ __forceinline__ unsigned short f2bf(float f) {
  unsigned int u = __float_as_uint(f);
  u += 0x7FFFu + ((u >> 16) & 1u);
  return (unsigned short)(u >> 16);
}

static __device__ __forceinline__ unsigned int cvtpk(float lo, float hi) {
  unsigned int r;
  asm("v_cvt_pk_bf16_f32 %0, %1, %2" : "=v"(r) : "v"(lo), "v"(hi));
  return r;
}

// dst' = {dst.lo32lanes, src.lo32lanes}, src' = {dst.hi32lanes, src.hi32lanes}
static __device__ __forceinline__ void plswap(unsigned int& a, unsigned int& b) {
  asm("v_permlane32_swap_b32 %0, %1" : "+v"(a), "+v"(b));
}

static __device__ __forceinline__ short8 mk8(unsigned int w0, unsigned int w1,
                                             unsigned int w2, unsigned int w3) {
  union { unsigned int u[4]; short8 s; } x;
  x.u[0] = w0; x.u[1] = w1; x.u[2] = w2; x.u[3] = w3;
  return x.s;
}

static __device__ __forceinline__ void gload_lds16(const void* g, void* l) {
  __builtin_amdgcn_global_load_lds(
      (const __attribute__((address_space(1))) unsigned int*)g,
      (__attribute__((address_space(3))) unsigned int*)l, 16, 0, 0);
}

// ---------------- merged prep: convert x, convert weights, mask scan ----------------
__global__ __launch_bounds__(256) void k_prep(const float* __restrict__ x,
                                              const float* __restrict__ Wq,
                                              const float* __restrict__ Wk,
                                              const float* __restrict__ Wv,
                                              const float* __restrict__ Wo,
                                              const float* __restrict__ mask,
                                              unsigned short* __restrict__ xb,
                                              unsigned short* __restrict__ wcat,
                                              unsigned short* __restrict__ wo_b,
                                              unsigned char* __restrict__ flags) {
  const int blk = blockIdx.x;
  const int t = threadIdx.x;
  if (blk < 4096) {                       // ---- convert x ----
    size_t i = ((size_t)blk * 256 + t) * 4;
    float4 v = *(const float4*)(x + i);
    u16x4 o = { f2bf(v.x), f2bf(v.y), f2bf(v.z), f2bf(v.w) };
    *(u16x4*)(xb + i) = o;
  } else if (blk < 6656) {                // ---- convert weights ----
    int r = blk - 4096;
    int c = t * 4;
    const float* src;
    unsigned short* dst;
    if (r < 1024)      { src = Wq + (size_t)r * 1024;          dst = wcat + (size_t)r * 1024; }
    else if (r < 1280) { src = Wk + (size_t)(r - 1024) * 1024; dst = wcat + (size_t)r * 1024; }
    else if (r < 1536) { src = Wv + (size_t)(r - 1280) * 1024; dst = wcat + (size_t)r * 1024; }
    else               { src = Wo + (size_t)(r - 1536) * 1024; dst = wo_b + (size_t)(r - 1536) * 1024; }
    float4 v = *(const float4*)(src + c);
    u16x4 o = { f2bf(v.x), f2bf(v.y), f2bf(v.z), f2bf(v.w) };
    *(u16x4*)(dst + c) = o;
  } else {                                // ---- mask block-zero scan ----
    const int mb = blk - 6656;            // b*1024 + qb*32 + kb
    const int b = mb >> 10, qb = (mb >> 5) & 31, kb = mb & 31;
    const float* base = mask + ((size_t)b * L_ + qb * 64) * L_ + kb * 64;
    const int r0 = t >> 4, c = (t & 15) * 4;
    bool nz = false;
#pragma unroll
    for (int i = 0; i < 4; ++i) {
      float4 v = *(const float4*)(base + (size_t)(r0 + i * 16) * L_ + c);
      nz |= (v.x != 0.f) | (v.y != 0.f) | (v.z != 0.f) | (v.w != 0.f);
    }
    __shared__ int anyv;
    if (t == 0) anyv = 0;
    __syncthreads();
    if (__any(nz) && (t & 63) == 0) atomicOr(&anyv, 1);
    __syncthreads();
    if (t == 0) flags[mb] = (unsigned char)anyv;
  }
}

// ---------------- GEMM (128x128, BK=64, XOR-swizzle, 2-phase dbuf pipeline) ----------------
template <int MODE>
__global__ __launch_bounds__(256) void k_gemm(const unsigned short* __restrict__ A,
                                              const unsigned short* __restrict__ Bt,
                                              const float* __restrict__ bias0,
                                              const float* __restrict__ bias1,
                                              const float* __restrict__ bias2,
                                              unsigned short* __restrict__ q_ws,
                                              unsigned short* __restrict__ k_ws,
                                              unsigned short* __restrict__ vt_ws,
                                              float* __restrict__ outp) {
  const int bn = blockIdx.x, bm = blockIdx.y;
  const int t = threadIdx.x;
  const int lane = t & 63, li = lane & 15, g = lane >> 4;
  const int wid = t >> 6, wr = wid >> 1, wc = wid & 1;
  __shared__ unsigned short lds_a[2][128 * 64];   // [buf][row][slot], slot s holds G col s^(row&7)
  __shared__ unsigned short lds_b[2][128 * 64];

  const f32x4 z = {0.f, 0.f, 0.f, 0.f};
  f32x4 acc[4][4];
#pragma unroll
  for (int m = 0; m < 4; ++m)
#pragma unroll
    for (int n = 0; n < 4; ++n) acc[m][n] = z;

  // staging: 4 chunks of 256 threads cover 1024 granule-slots (128 rows x 8 slots)
  const unsigned short* asrc[4];
  const unsigned short* bsrc[4];
  int ldst[4];
#pragma unroll
  for (int c = 0; c < 4; ++c) {
    const int idx = c * 256 + t, row = idx >> 3, sl = idx & 7;
    const int gcol = (sl ^ (row & 7)) * 8;
    asrc[c] = A  + (size_t)(bm * 128 + row) * 1024 + gcol;
    bsrc[c] = Bt + (size_t)(bn * 128 + row) * 1024 + gcol;
    ldst[c] = idx * 8;
  }
  const int rs = li & 7;

#define GSTAGE(buf, kc)                                                  \
  {                                                                      \
    _Pragma("unroll")                                                    \
    for (int c = 0; c < 4; ++c) {                                        \
      gload_lds16(asrc[c] + (kc), &lds_a[buf][ldst[c]]);                 \
      gload_lds16(bsrc[c] + (kc), &lds_b[buf][ldst[c]]);                 \
    }                                                                    \
  }

  GSTAGE(0, 0);
  __syncthreads();                        // buf0 ready

#pragma unroll 1
  for (int it = 0; it < 16; ++it) {
    const int cur = it & 1;
    if (it + 1 < 16) GSTAGE(cur ^ 1, (it + 1) * 64);   // issue next tile first (T3-min)
#pragma unroll
    for (int ks = 0; ks < 2; ++ks) {
      short8 af[4], bf[4];
#pragma unroll
      for (int m = 0; m < 4; ++m)
        af[m] = *(const short8*)&lds_a[cur][(wr * 64 + m * 16 + li) * 64 + (((ks * 4 + g) ^ rs) * 8)];
#pragma unroll
      for (int n = 0; n < 4; ++n)
        bf[n] = *(const short8*)&lds_b[cur][(wc * 64 + n * 16 + li) * 64 + (((ks * 4 + g) ^ rs) * 8)];
#pragma unroll
      for (int m = 0; m < 4; ++m)
#pragma unroll
        for (int n = 0; n < 4; ++n)
          acc[m][n] = MFMA(af[m], bf[n], acc[m][n], 0, 0, 0);
    }
    __syncthreads();    // drains this iter's GSTAGE (vmcnt) + all reads of cur (lgkm)
  }
#undef GSTAGE

#pragma unroll
  for (int m = 0; m < 4; ++m) {
    const int row0 = bm * 128 + wr * 64 + m * 16 + 4 * g;
#pragma unroll
    for (int n = 0; n < 4; ++n) {
      const int col = bn * 128 + wc * 64 + n * 16 + li;
      f32x4 v = acc[m][n];
      if (MODE == 1) {
        const float bias = bias0[col];
#pragma unroll
        for (int r = 0; r < 4; ++r) outp[(size_t)(row0 + r) * 1024 + col] = v[r] + bias;
      } else {
        if (col < 1024) {
          const float bias = bias0[col];
#pragma unroll
          for (int r = 0; r < 4; ++r) q_ws[(size_t)(row0 + r) * 1024 + col] = f2bf((v[r] + bias) * QSC);
        } else if (col < 1280) {
          const int cc = col - 1024;
          const float bias = bias1[cc];
#pragma unroll
          for (int r = 0; r < 4; ++r) k_ws[(size_t)(row0 + r) * 256 + cc] = f2bf(v[r] + bias);
        } else {
          const int cc = col - 1280;
          const float bias = bias2[cc];
          const int kvh = cc >> 6, d = cc & 63;
          const int b = row0 >> 11, l0 = row0 & 2047;
          u16x4 pk = { f2bf(v[0] + bias), f2bf(v[1] + bias), f2bf(v[2] + bias), f2bf(v[3] + bias) };
          *(u16x4*)(vt_ws + ((size_t)((b * KVH_ + kvh) * 64 + d)) * 2048 + l0) = pk;
        }
      }
    }
  }
}

// ---------------- flash attention (GQA, 8 waves: (kj-half, head), 32x32 MFMA, reg-P) ----------------
// R9 configuration (best measured: 49.2 us, VGPR 64, zero spill). grid (B*KVH=8, L/32=64),
// 512 threads, wave (kh,h): head h over kj-slice kh. T14 reg-staging (loads issued one
// iteration early -> vmcnt(0) free), raw lgkmcnt-only barriers (staged global loads stay
// in flight across the barrier), max-free softmax, in-register P (cvt_pk + permlane32_swap).
__global__ __launch_bounds__(512, 4) void k_attn(const unsigned short* __restrict__ q_ws,
                                                 const unsigned short* __restrict__ k_ws,
                                                 const unsigned short* __restrict__ vt_ws,
                                                 const float* __restrict__ mask,
                                                 const unsigned char* __restrict__ mflags,
                                                 unsigned short* __restrict__ ctx) {
  const int bk = blockIdx.x;            // b*4 + kvh (== XCD id -> L2 locality)
  const int qt = blockIdx.y;            // 32-row q tile
  const int b = bk >> 2, kvh = bk & 3;
  const int t = threadIdx.x;            // 0..511
  const int wid = t >> 6, lane = t & 63;
  const int l31 = lane & 31, g1 = lane >> 5;
  const int h = wid & 3, kh = wid >> 2;

  __shared__ unsigned short smem[16384];   // 32KB: 2 bufs x [K 8KB | V 8KB]
  __shared__ float lred[4][64];            // [h][lane] l partials from kh=1

  // ---- Q frags: B-operand of 32x32x16: n=q=l31, k=d = ks*16 + g1*8 + j ----
  const unsigned short* qbase = q_ws + ((size_t)b * L_ + qt * 32 + l31) * H_ +
                                (kvh * 4 + h) * 64 + g1 * 8;
  short8 qf[4];
#pragma unroll
  for (int ks = 0; ks < 4; ++ks) qf[ks] = *(const short8*)(qbase + ks * 16);

  // ---- mask flags -> register bitmask ----
  const unsigned int* fp = (const unsigned int*)(mflags + b * 1024 + (qt >> 1) * 32);
  unsigned int fm = 0;
#pragma unroll
  for (int w = 0; w < 8; ++w) {
    unsigned int wv = fp[w];
    fm |= ((wv & 0x000000FFu) ? 1u : 0u) << (w * 4 + 0);
    fm |= ((wv & 0x0000FF00u) ? 1u : 0u) << (w * 4 + 1);
    fm |= ((wv & 0x00FF0000u) ? 1u : 0u) << (w * 4 + 2);
    fm |= ((wv & 0xFF000000u) ? 1u : 0u) << (w * 4 + 3);
  }
  fm = __builtin_amdgcn_readfirstlane(fm);

  // ---- staging sources (pre-swizzled granules, rule #21); thread t: row t>>3, slot t&7 ----
  const int srow = t >> 3, sgr = t & 7;
  const int swz = (sgr ^ (srow & 7)) * 8;
  const unsigned short* ksrc = k_ws + ((size_t)b * L_ + srow) * 256 + kvh * 64 + swz;
  const unsigned short* vsrc = vt_ws + ((size_t)(b * KVH_ + kvh) * 64 + srow) * 2048 + swz;

  const f32x16 z16 = {0,0,0,0,0,0,0,0,0,0,0,0,0,0,0,0};
  f32x16 o_[2];                           // [db] : O^T[d = db*32 + row][q]
  o_[0] = z16; o_[1] = z16;
  float l_part = 0.f;

  const int rK = kh * 32 + l31, swK = rK & 7;
  const int swV = l31 & 7;                // (db*32 + l31) & 7, both db

  short8 kst, vst;                        // staged regs (tile kt+1)
#define LOADR(kt) { kst = *(const short8*)(ksrc + (size_t)(kt) * 16384); \
                    vst = *(const short8*)(vsrc + (kt) * 64); }
#define WRITES(buf) { unsigned short* dk = smem + (buf) * 8192;          \
                      *(short8*)(dk + t * 8) = kst;                      \
                      *(short8*)(dk + 4096 + t * 8) = vst; }

  // prologue: buf0 = tile 0 (visible), regs = tile 1 (may be in flight)
  LOADR(0);
  WRITES(0);                              // compiler waits vmcnt for kst/vst use
  LOADR(1);
  __syncthreads();                        // one full drain; invariant established

#pragma unroll 1
  for (int kt = 0; kt < 32; ++kt) {
    const int cur = kt & 1;
    const unsigned short* lk = smem + cur * 8192;
    const unsigned short* lv = lk + 4096;

    // ---- K/V frags of tile kt ----
    short8 kf[4];
#pragma unroll
    for (int ks = 0; ks < 4; ++ks)
      kf[ks] = *(const short8*)&lk[rK * 64 + ((ks * 2 + g1) ^ swK) * 8];
    short8 vf[2][2];
#pragma unroll
    for (int db = 0; db < 2; ++db)
#pragma unroll
      for (int s = 0; s < 2; ++s)
        vf[db][s] = *(const short8*)&lv[(db * 32 + l31) * 64 + ((kh * 4 + s * 2 + g1) ^ swV) * 8];

    // ---- T14: regs(kt+1) landed (issued a full iter ago) -> write-late, then issue kt+2
    asm volatile("s_waitcnt vmcnt(0)" ::: "memory");
    if (kt + 1 < 32) WRITES(cur ^ 1);
    if (kt + 2 < 32) LOADR(kt + 2);

    // ---- S^T[32kj x 32q] = K * Q^T ----
    f32x16 sv = z16;
    __builtin_amdgcn_s_setprio(1);
#pragma unroll
    for (int ks = 0; ks < 4; ++ks) sv = MFMA32(kf[ks], qf[ks], sv, 0, 0, 0);
    __builtin_amdgcn_s_setprio(0);

    if (fm & (1u << kt)) {                 // rare: mask block nonzero
      const float* mrow = mask + ((size_t)b * L_ + qt * 32 + l31) * L_ + kt * 64 + kh * 32 + g1 * 4;
#pragma unroll
      for (int rg = 0; rg < 4; ++rg) {
        float4 mv = *(const float4*)(mrow + rg * 8);
#pragma unroll
        for (int j = 0; j < 4; ++j) sv[rg * 4 + j] = fmaf((&mv.x)[j], LOG2E, sv[rg * 4 + j]);
      }
    }

    // ---- max-free softmax + in-register P re-layout (cvt_pk + permlane32_swap) ----
    float e[16];
#pragma unroll
    for (int r = 0; r < 16; ++r) e[r] = EXP2(sv[r]);
    l_part += (((e[0] + e[1]) + (e[2] + e[3])) + ((e[4] + e[5]) + (e[6] + e[7]))) +
              (((e[8] + e[9]) + (e[10] + e[11])) + ((e[12] + e[13]) + (e[14] + e[15])));
    unsigned int w0 = cvtpk(e[0], e[1]),   w1 = cvtpk(e[2], e[3]);
    unsigned int w2 = cvtpk(e[4], e[5]),   w3 = cvtpk(e[6], e[7]);
    unsigned int w4 = cvtpk(e[8], e[9]),   w5 = cvtpk(e[10], e[11]);
    unsigned int w6 = cvtpk(e[12], e[13]), w7 = cvtpk(e[14], e[15]);
    plswap(w0, w2); plswap(w1, w3);        // kstep 0
    plswap(w4, w6); plswap(w5, w7);        // kstep 1
    short8 pa0 = mk8(w0, w1, w2, w3);
    short8 pa1 = mk8(w4, w5, w6, w7);

    // ---- PV: O^T[d][q] += V^T * P^T ----
    __builtin_amdgcn_s_setprio(1);
#pragma unroll
    for (int db = 0; db < 2; ++db) {
      o_[db] = MFMA32(vf[db][0], pa0, o_[db], 0, 0, 0);
      o_[db] = MFMA32(vf[db][1], pa1, o_[db], 0, 0, 0);
    }
    __builtin_amdgcn_s_setprio(0);

    // ---- raw barrier: ds_writes visible; kt+2 global loads stay in flight ----
    asm volatile("s_waitcnt lgkmcnt(0)" ::: "memory");
    __builtin_amdgcn_s_barrier();
    __builtin_amdgcn_sched_barrier(0);
  }
#undef LOADR
#undef WRITES

  // ---- epilogue: merge kh partials via LDS (coalesced 16B/lane layout) ----
  float lt = l_part + __shfl_xor(l_part, 32);
  float* red = (float*)smem;              // reuse: [(h*2+db)*4 + w4][lane][4]

  if (kh == 1) {
    lred[h][lane] = lt;
#pragma unroll
    for (int db = 0; db < 2; ++db)
#pragma unroll
      for (int w4 = 0; w4 < 4; ++w4) {
        f32x4 pv = { o_[db][w4 * 4 + 0], o_[db][w4 * 4 + 1],
                     o_[db][w4 * 4 + 2], o_[db][w4 * 4 + 3] };
        *(f32x4*)&red[(((h * 2 + db) * 4 + w4) * 64 + lane) * 4] = pv;
      }
  }
  __syncthreads();

  if (kh == 0) {
    const float inv = 1.f / (lt + lred[h][lane]);
#pragma unroll
    for (int db = 0; db < 2; ++db) {
      f32x16 acc = o_[db];
#pragma unroll
      for (int w4 = 0; w4 < 4; ++w4) {
        f32x4 pv = *(const f32x4*)&red[(((h * 2 + db) * 4 + w4) * 64 + lane) * 4];
#pragma unroll
        for (int j = 0; j < 4; ++j) acc[w4 * 4 + j] += pv[j];
      }
      unsigned short* cp = ctx + ((size_t)b * L_ + qt * 32 + l31) * H_ +
                           (kvh * 4 + h) * 64 + db * 32 + g1 * 4;
#pragma unroll
      for (int k4 = 0; k4 < 4; ++k4) {
        unsigned int a0 = cvtpk(acc[4 * k4 + 0] * inv, acc[4 * k4 + 1] * inv);
        unsigned int a1 = cvtpk(acc[4 * k4 + 2] * inv, acc[4 * k4 + 3] * inv);
        *(unsigned int*)(cp + 8 * k4) = a0;
        *(unsigned int*)(cp + 8 * k4 + 2) = a1;
      }
    }
  }
}

// ---------------- launch ----------------
extern "C" void kernel_launch(void* const* d_in, const int* in_sizes, int n_in,
                              void* d_out, int out_size, void* d_ws, size_t ws_size,
                              hipStream_t stream) {
  const float* x    = (const float*)d_in[0];
  const float* mask = (const float*)d_in[1];
  const float* Wq   = (const float*)d_in[2];
  const float* bq   = (const float*)d_in[3];
  const float* Wk   = (const float*)d_in[4];
  const float* bk   = (const float*)d_in[5];
  const float* Wv   = (const float*)d_in[6];
  const float* bv   = (const float*)d_in[7];
  const float* Wo   = (const float*)d_in[8];
  const float* bo   = (const float*)d_in[9];
  float* out = (float*)d_out;

  char* ws = (char*)d_ws;
  unsigned short* xb    = (unsigned short*)(ws);                 // 8 MB (reused as ctx)
  unsigned short* ctx   = xb;
  unsigned short* wcat  = (unsigned short*)(ws + 8388608);       // 3 MB
  unsigned short* wo_b  = (unsigned short*)(ws + 11534336);      // 2 MB
  unsigned short* q_ws  = (unsigned short*)(ws + 13631488);      // 8 MB
  unsigned short* k_ws  = (unsigned short*)(ws + 22020096);      // 2 MB
  unsigned short* vt_ws = (unsigned short*)(ws + 24117248);      // 2 MB
  unsigned char*  mflg  = (unsigned char*)(ws + 26214400);       // 2 KB

  k_prep<<<dim3(8704), dim3(256), 0, stream>>>(x, Wq, Wk, Wv, Wo, mask, xb, wcat, wo_b, mflg);
  k_gemm<0><<<dim3(12, 32), dim3(256), 0, stream>>>(xb, wcat, bq, bk, bv, q_ws, k_ws, vt_ws, nullptr);
  k_attn<<<dim3(8, 64), dim3(512), 0, stream>>>(q_ws, k_ws, vt_ws, mask, mflg, ctx);
  k_gemm<1><<<dim3(8, 32), dim3(256), 0, stream>>>(ctx, wo_b, bo, nullptr, nullptr,
                                                   nullptr, nullptr, nullptr, out);
}

// Round 14
// 104.838 us; speedup vs baseline: 5.8831x; 1.0071x over previous
//
#include <hip/hip_runtime.h>

#define B_   2
#define L_   2048
#define H_   1024
#define NH_  16
#define KVH_ 4
#define HD_  64

typedef short short8 __attribute__((ext_vector_type(8)));
typedef float f32x4 __attribute__((ext_vector_type(4)));
typedef float f32x16 __attribute__((ext_vector_type(16)));
typedef unsigned short u16x4 __attribute__((ext_vector_type(4)));

#define LOG2E 1.4426950408889634f
#define QSC   0.18033688011112042f   /* 0.125 * log2(e) */
#define MFMA   __builtin_amdgcn_mfma_f32_16x16x32_bf16
#define MFMA32 __builtin_amdgcn_mfma_f32_32x32x16_bf16

#if __has_builtin(__builtin_amdgcn_exp2f)
#define EXP2(x) __builtin_amdgcn_exp2f(x)
#else
#define EXP2(x) exp2f(x)
#endif

static __device__ __forceinline__ unsigned short f2bf(float f) {
  unsigned int u = __float_as_uint(f);
  u += 0x7FFFu + ((u >> 16) & 1u);
  return (unsigned short)(u >> 16);
}

static __device__ __forceinline__ unsigned int cvtpk(float lo, float hi) {
  unsigned int r;
  asm("v_cvt_pk_bf16_f32 %0, %1, %2" : "=v"(r) : "v"(lo), "v"(hi));
  return r;
}

// dst' = {dst.lo32lanes, src.lo32lanes}, src' = {dst.hi32lanes, src.hi32lanes}
static __device__ __forceinline__ void plswap(unsigned int& a, unsigned int& b) {
  asm("v_permlane32_swap_b32 %0, %1" : "+v"(a), "+v"(b));
}

static __device__ __forceinline__ short8 mk8(unsigned int w0, unsigned int w1,
                                             unsigned int w2, unsigned int w3) {
  union { unsigned int u[4]; short8 s; } x;
  x.u[0] = w0; x.u[1] = w1; x.u[2] = w2; x.u[3] = w3;
  return x.s;
}

static __device__ __forceinline__ void gload_lds16(const void* g, void* l) {
  __builtin_amdgcn_global_load_lds(
      (const __attribute__((address_space(1))) unsigned int*)g,
      (__attribute__((address_space(3))) unsigned int*)l, 16, 0, 0);
}

// ---------------- merged prep: convert x, convert weights, mask scan ----------------
__global__ __launch_bounds__(256) void k_prep(const float* __restrict__ x,
                                              const float* __restrict__ Wq,
                                              const float* __restrict__ Wk,
                                              const float* __restrict__ Wv,
                                              const float* __restrict__ Wo,
                                              const float* __restrict__ mask,
                                              unsigned short* __restrict__ xb,
                                              unsigned short* __restrict__ wcat,
                                              unsigned short* __restrict__ wo_b,
                                              unsigned char* __restrict__ flags) {
  const int blk = blockIdx.x;
  const int t = threadIdx.x;
  if (blk < 4096) {                       // ---- convert x ----
    size_t i = ((size_t)blk * 256 + t) * 4;
    float4 v = *(const float4*)(x + i);
    u16x4 o = { f2bf(v.x), f2bf(v.y), f2bf(v.z), f2bf(v.w) };
    *(u16x4*)(xb + i) = o;
  } else if (blk < 6656) {                // ---- convert weights ----
    int r = blk - 4096;
    int c = t * 4;
    const float* src;
    unsigned short* dst;
    if (r < 1024)      { src = Wq + (size_t)r * 1024;          dst = wcat + (size_t)r * 1024; }
    else if (r < 1280) { src = Wk + (size_t)(r - 1024) * 1024; dst = wcat + (size_t)r * 1024; }
    else if (r < 1536) { src = Wv + (size_t)(r - 1280) * 1024; dst = wcat + (size_t)r * 1024; }
    else               { src = Wo + (size_t)(r - 1536) * 1024; dst = wo_b + (size_t)(r - 1536) * 1024; }
    float4 v = *(const float4*)(src + c);
    u16x4 o = { f2bf(v.x), f2bf(v.y), f2bf(v.z), f2bf(v.w) };
    *(u16x4*)(dst + c) = o;
  } else {                                // ---- mask block-zero scan ----
    const int mb = blk - 6656;            // b*1024 + qb*32 + kb
    const int b = mb >> 10, qb = (mb >> 5) & 31, kb = mb & 31;
    const float* base = mask + ((size_t)b * L_ + qb * 64) * L_ + kb * 64;
    const int r0 = t >> 4, c = (t & 15) * 4;
    bool nz = false;
#pragma unroll
    for (int i = 0; i < 4; ++i) {
      float4 v = *(const float4*)(base + (size_t)(r0 + i * 16) * L_ + c);
      nz |= (v.x != 0.f) | (v.y != 0.f) | (v.z != 0.f) | (v.w != 0.f);
    }
    __shared__ int anyv;
    if (t == 0) anyv = 0;
    __syncthreads();
    if (__any(nz) && (t & 63) == 0) atomicOr(&anyv, 1);
    __syncthreads();
    if (t == 0) flags[mb] = (unsigned char)anyv;
  }
}

// ---------------- GEMM (BMx128, BK=64, XOR-swizzle, 2-phase dbuf pipeline) ----------------
// BM=64 for the QKV GEMM: grid (12,64)=768 blocks = exactly 3 blocks/CU (no tail
// quantization; the old (12,32)=384 = 1.5/CU wasted ~1/3 of the dispatch).
// BM=128 for the out-projection: (8,32)=256 = exactly 1/CU.
template <int MODE, int BM>
__global__ __launch_bounds__(256, BM == 64 ? 3 : 2)
void k_gemm(const unsigned short* __restrict__ A,
            const unsigned short* __restrict__ Bt,
            const float* __restrict__ bias0,
            const float* __restrict__ bias1,
            const float* __restrict__ bias2,
            unsigned short* __restrict__ q_ws,
            unsigned short* __restrict__ k_ws,
            unsigned short* __restrict__ vt_ws,
            float* __restrict__ outp) {
  constexpr int MR = BM / 32;             // M-frags per wave (wave covers BM/2 rows)
  constexpr int ACH = BM * 8 / 256;       // A staging chunks
  const int bn = blockIdx.x, bm = blockIdx.y;
  const int t = threadIdx.x;
  const int lane = t & 63, li = lane & 15, g = lane >> 4;
  const int wid = t >> 6, wr = wid >> 1, wc = wid & 1;
  __shared__ unsigned short lds_a[2][BM * 64];    // [buf][row][slot], slot s = G col s^(row&7)
  __shared__ unsigned short lds_b[2][128 * 64];

  const f32x4 z = {0.f, 0.f, 0.f, 0.f};
  f32x4 acc[MR][4];
#pragma unroll
  for (int m = 0; m < MR; ++m)
#pragma unroll
    for (int n = 0; n < 4; ++n) acc[m][n] = z;

  const unsigned short* asrc[ACH];
  const unsigned short* bsrc[4];
  int adst[ACH], bdst[4];
#pragma unroll
  for (int c = 0; c < ACH; ++c) {
    const int idx = c * 256 + t, row = idx >> 3, sl = idx & 7;
    asrc[c] = A + (size_t)(bm * BM + row) * 1024 + ((sl ^ (row & 7)) * 8);
    adst[c] = idx * 8;
  }
#pragma unroll
  for (int c = 0; c < 4; ++c) {
    const int idx = c * 256 + t, row = idx >> 3, sl = idx & 7;
    bsrc[c] = Bt + (size_t)(bn * 128 + row) * 1024 + ((sl ^ (row & 7)) * 8);
    bdst[c] = idx * 8;
  }
  const int rs = li & 7;

#define GSTAGE(buf, kc)                                                  \
  {                                                                      \
    _Pragma("unroll")                                                    \
    for (int c = 0; c < ACH; ++c) gload_lds16(asrc[c] + (kc), &lds_a[buf][adst[c]]); \
    _Pragma("unroll")                                                    \
    for (int c = 0; c < 4; ++c)   gload_lds16(bsrc[c] + (kc), &lds_b[buf][bdst[c]]); \
  }

  GSTAGE(0, 0);
  __syncthreads();                        // buf0 ready

#pragma unroll 1
  for (int it = 0; it < 16; ++it) {
    const int cur = it & 1;
    if (it + 1 < 16) GSTAGE(cur ^ 1, (it + 1) * 64);   // issue next tile first (T3-min)
#pragma unroll
    for (int ks = 0; ks < 2; ++ks) {
      short8 af[MR], bf[4];
#pragma unroll
      for (int m = 0; m < MR; ++m)
        af[m] = *(const short8*)&lds_a[cur][(wr * (BM / 2) + m * 16 + li) * 64 +
                                            (((ks * 4 + g) ^ rs) * 8)];
#pragma unroll
      for (int n = 0; n < 4; ++n)
        bf[n] = *(const short8*)&lds_b[cur][(wc * 64 + n * 16 + li) * 64 +
                                            (((ks * 4 + g) ^ rs) * 8)];
#pragma unroll
      for (int m = 0; m < MR; ++m)
#pragma unroll
        for (int n = 0; n < 4; ++n)
          acc[m][n] = MFMA(af[m], bf[n], acc[m][n], 0, 0, 0);
    }
    __syncthreads();    // drains this iter's GSTAGE (vmcnt) + all reads of cur (lgkm)
  }
#undef GSTAGE

#pragma unroll
  for (int m = 0; m < MR; ++m) {
    const int row0 = bm * BM + wr * (BM / 2) + m * 16 + 4 * g;
#pragma unroll
    for (int n = 0; n < 4; ++n) {
      const int col = bn * 128 + wc * 64 + n * 16 + li;
      f32x4 v = acc[m][n];
      if (MODE == 1) {
        const float bias = bias0[col];
#pragma unroll
        for (int r = 0; r < 4; ++r) outp[(size_t)(row0 + r) * 1024 + col] = v[r] + bias;
      } else {
        if (col < 1024) {
          const float bias = bias0[col];
#pragma unroll
          for (int r = 0; r < 4; ++r) q_ws[(size_t)(row0 + r) * 1024 + col] = f2bf((v[r] + bias) * QSC);
        } else if (col < 1280) {
          const int cc = col - 1024;
          const float bias = bias1[cc];
#pragma unroll
          for (int r = 0; r < 4; ++r) k_ws[(size_t)(row0 + r) * 256 + cc] = f2bf(v[r] + bias);
        } else {
          const int cc = col - 1280;
          const float bias = bias2[cc];
          const int kvh = cc >> 6, d = cc & 63;
          const int b = row0 >> 11, l0 = row0 & 2047;
          u16x4 pk = { f2bf(v[0] + bias), f2bf(v[1] + bias), f2bf(v[2] + bias), f2bf(v[3] + bias) };
          *(u16x4*)(vt_ws + ((size_t)((b * KVH_ + kvh) * 64 + d)) * 2048 + l0) = pk;
        }
      }
    }
  }
}

// ---------------- flash attention (GQA, 8 waves: (kj-half, head), 32x32 MFMA, reg-P) ----------------
// R9 configuration (best measured: 48.4 us, VGPR 64, zero spill). grid (B*KVH=8, L/32=64),
// 512 threads, wave (kh,h): head h over kj-slice kh. T14 reg-staging (loads issued one
// iteration early -> vmcnt(0) free), raw lgkmcnt-only barriers (staged global loads stay
// in flight across the barrier), max-free softmax, in-register P (cvt_pk + permlane32_swap).
__global__ __launch_bounds__(512, 4) void k_attn(const unsigned short* __restrict__ q_ws,
                                                 const unsigned short* __restrict__ k_ws,
                                                 const unsigned short* __restrict__ vt_ws,
                                                 const float* __restrict__ mask,
                                                 const unsigned char* __restrict__ mflags,
                                                 unsigned short* __restrict__ ctx) {
  const int bk = blockIdx.x;            // b*4 + kvh (== XCD id -> L2 locality)
  const int qt = blockIdx.y;            // 32-row q tile
  const int b = bk >> 2, kvh = bk & 3;
  const int t = threadIdx.x;            // 0..511
  const int wid = t >> 6, lane = t & 63;
  const int l31 = lane & 31, g1 = lane >> 5;
  const int h = wid & 3, kh = wid >> 2;

  __shared__ unsigned short smem[16384];   // 32KB: 2 bufs x [K 8KB | V 8KB]
  __shared__ float lred[4][64];            // [h][lane] l partials from kh=1

  // ---- Q frags: B-operand of 32x32x16: n=q=l31, k=d = ks*16 + g1*8 + j ----
  const unsigned short* qbase = q_ws + ((size_t)b * L_ + qt * 32 + l31) * H_ +
                                (kvh * 4 + h) * 64 + g1 * 8;
  short8 qf[4];
#pragma unroll
  for (int ks = 0; ks < 4; ++ks) qf[ks] = *(const short8*)(qbase + ks * 16);

  // ---- mask flags -> register bitmask ----
  const unsigned int* fp = (const unsigned int*)(mflags + b * 1024 + (qt >> 1) * 32);
  unsigned int fm = 0;
#pragma unroll
  for (int w = 0; w < 8; ++w) {
    unsigned int wv = fp[w];
    fm |= ((wv & 0x000000FFu) ? 1u : 0u) << (w * 4 + 0);
    fm |= ((wv & 0x0000FF00u) ? 1u : 0u) << (w * 4 + 1);
    fm |= ((wv & 0x00FF0000u) ? 1u : 0u) << (w * 4 + 2);
    fm |= ((wv & 0xFF000000u) ? 1u : 0u) << (w * 4 + 3);
  }
  fm = __builtin_amdgcn_readfirstlane(fm);

  // ---- staging sources (pre-swizzled granules, rule #21); thread t: row t>>3, slot t&7 ----
  const int srow = t >> 3, sgr = t & 7;
  const int swz = (sgr ^ (srow & 7)) * 8;
  const unsigned short* ksrc = k_ws + ((size_t)b * L_ + srow) * 256 + kvh * 64 + swz;
  const unsigned short* vsrc = vt_ws + ((size_t)(b * KVH_ + kvh) * 64 + srow) * 2048 + swz;

  const f32x16 z16 = {0,0,0,0,0,0,0,0,0,0,0,0,0,0,0,0};
  f32x16 o_[2];                           // [db] : O^T[d = db*32 + row][q]
  o_[0] = z16; o_[1] = z16;
  float l_part = 0.f;

  const int rK = kh * 32 + l31, swK = rK & 7;
  const int swV = l31 & 7;                // (db*32 + l31) & 7, both db

  short8 kst, vst;                        // staged regs (tile kt+1)
#define LOADR(kt) { kst = *(const short8*)(ksrc + (size_t)(kt) * 16384); \
                    vst = *(const short8*)(vsrc + (kt) * 64); }
#define WRITES(buf) { unsigned short* dk = smem + (buf) * 8192;          \
                      *(short8*)(dk + t * 8) = kst;                      \
                      *(short8*)(dk + 4096 + t * 8) = vst; }

  // prologue: buf0 = tile 0 (visible), regs = tile 1 (may be in flight)
  LOADR(0);
  WRITES(0);                              // compiler waits vmcnt for kst/vst use
  LOADR(1);
  __syncthreads();                        // one full drain; invariant established

#pragma unroll 1
  for (int kt = 0; kt < 32; ++kt) {
    const int cur = kt & 1;
    const unsigned short* lk = smem + cur * 8192;
    const unsigned short* lv = lk + 4096;

    // ---- K/V frags of tile kt ----
    short8 kf[4];
#pragma unroll
    for (int ks = 0; ks < 4; ++ks)
      kf[ks] = *(const short8*)&lk[rK * 64 + ((ks * 2 + g1) ^ swK) * 8];
    short8 vf[2][2];
#pragma unroll
    for (int db = 0; db < 2; ++db)
#pragma unroll
      for (int s = 0; s < 2; ++s)
        vf[db][s] = *(const short8*)&lv[(db * 32 + l31) * 64 + ((kh * 4 + s * 2 + g1) ^ swV) * 8];

    // ---- T14: regs(kt+1) landed (issued a full iter ago) -> write-late, then issue kt+2
    asm volatile("s_waitcnt vmcnt(0)" ::: "memory");
    if (kt + 1 < 32) WRITES(cur ^ 1);
    if (kt + 2 < 32) LOADR(kt + 2);

    // ---- S^T[32kj x 32q] = K * Q^T ----
    f32x16 sv = z16;
    __builtin_amdgcn_s_setprio(1);
#pragma unroll
    for (int ks = 0; ks < 4; ++ks) sv = MFMA32(kf[ks], qf[ks], sv, 0, 0, 0);
    __builtin_amdgcn_s_setprio(0);

    if (fm & (1u << kt)) {                 // rare: mask block nonzero
      const float* mrow = mask + ((size_t)b * L_ + qt * 32 + l31) * L_ + kt * 64 + kh * 32 + g1 * 4;
#pragma unroll
      for (int rg = 0; rg < 4; ++rg) {
        float4 mv = *(const float4*)(mrow + rg * 8);
#pragma unroll
        for (int j = 0; j < 4; ++j) sv[rg * 4 + j] = fmaf((&mv.x)[j], LOG2E, sv[rg * 4 + j]);
      }
    }

    // ---- max-free softmax + in-register P re-layout (cvt_pk + permlane32_swap) ----
    float e[16];
#pragma unroll
    for (int r = 0; r < 16; ++r) e[r] = EXP2(sv[r]);
    l_part += (((e[0] + e[1]) + (e[2] + e[3])) + ((e[4] + e[5]) + (e[6] + e[7]))) +
              (((e[8] + e[9]) + (e[10] + e[11])) + ((e[12] + e[13]) + (e[14] + e[15])));
    unsigned int w0 = cvtpk(e[0], e[1]),   w1 = cvtpk(e[2], e[3]);
    unsigned int w2 = cvtpk(e[4], e[5]),   w3 = cvtpk(e[6], e[7]);
    unsigned int w4 = cvtpk(e[8], e[9]),   w5 = cvtpk(e[10], e[11]);
    unsigned int w6 = cvtpk(e[12], e[13]), w7 = cvtpk(e[14], e[15]);
    plswap(w0, w2); plswap(w1, w3);        // kstep 0
    plswap(w4, w6); plswap(w5, w7);        // kstep 1
    short8 pa0 = mk8(w0, w1, w2, w3);
    short8 pa1 = mk8(w4, w5, w6, w7);

    // ---- PV: O^T[d][q] += V^T * P^T ----
    __builtin_amdgcn_s_setprio(1);
#pragma unroll
    for (int db = 0; db < 2; ++db) {
      o_[db] = MFMA32(vf[db][0], pa0, o_[db], 0, 0, 0);
      o_[db] = MFMA32(vf[db][1], pa1, o_[db], 0, 0, 0);
    }
    __builtin_amdgcn_s_setprio(0);

    // ---- raw barrier: ds_writes visible; kt+2 global loads stay in flight ----
    asm volatile("s_waitcnt lgkmcnt(0)" ::: "memory");
    __builtin_amdgcn_s_barrier();
    __builtin_amdgcn_sched_barrier(0);
  }
#undef LOADR
#undef WRITES

  // ---- epilogue: merge kh partials via LDS (coalesced 16B/lane layout) ----
  float lt = l_part + __shfl_xor(l_part, 32);
  float* red = (float*)smem;              // reuse: [(h*2+db)*4 + w4][lane][4]

  if (kh == 1) {
    lred[h][lane] = lt;
#pragma unroll
    for (int db = 0; db < 2; ++db)
#pragma unroll
      for (int w4 = 0; w4 < 4; ++w4) {
        f32x4 pv = { o_[db][w4 * 4 + 0], o_[db][w4 * 4 + 1],
                     o_[db][w4 * 4 + 2], o_[db][w4 * 4 + 3] };
        *(f32x4*)&red[(((h * 2 + db) * 4 + w4) * 64 + lane) * 4] = pv;
      }
  }
  __syncthreads();

  if (kh == 0) {
    const float inv = 1.f / (lt + lred[h][lane]);
#pragma unroll
    for (int db = 0; db < 2; ++db) {
      f32x16 acc = o_[db];
#pragma unroll
      for (int w4 = 0; w4 < 4; ++w4) {
        f32x4 pv = *(const f32x4*)&red[(((h * 2 + db) * 4 + w4) * 64 + lane) * 4];
#pragma unroll
        for (int j = 0; j < 4; ++j) acc[w4 * 4 + j] += pv[j];
      }
      unsigned short* cp = ctx + ((size_t)b * L_ + qt * 32 + l31) * H_ +
                           (kvh * 4 + h) * 64 + db * 32 + g1 * 4;
#pragma unroll
      for (int k4 = 0; k4 < 4; ++k4) {
        unsigned int a0 = cvtpk(acc[4 * k4 + 0] * inv, acc[4 * k4 + 1] * inv);
        unsigned int a1 = cvtpk(acc[4 * k4 + 2] * inv, acc[4 * k4 + 3] * inv);
        *(unsigned int*)(cp + 8 * k4) = a0;
        *(unsigned int*)(cp + 8 * k4 + 2) = a1;
      }
    }
  }
}

// ---------------- launch ----------------
extern "C" void kernel_launch(void* const* d_in, const int* in_sizes, int n_in,
                              void* d_out, int out_size, void* d_ws, size_t ws_size,
                              hipStream_t stream) {
  const float* x    = (const float*)d_in[0];
  const float* mask = (const float*)d_in[1];
  const float* Wq   = (const float*)d_in[2];
  const float* bq   = (const float*)d_in[3];
  const float* Wk   = (const float*)d_in[4];
  const float* bk   = (const float*)d_in[5];
  const float* Wv   = (const float*)d_in[6];
  const float* bv   = (const float*)d_in[7];
  const float* Wo   = (const float*)d_in[8];
  const float* bo   = (const float*)d_in[9];
  float* out = (float*)d_out;

  char* ws = (char*)d_ws;
  unsigned short* xb    = (unsigned short*)(ws);                 // 8 MB (reused as ctx)
  unsigned short* ctx   = xb;
  unsigned short* wcat  = (unsigned short*)(ws + 8388608);       // 3 MB
  unsigned short* wo_b  = (unsigned short*)(ws + 11534336);      // 2 MB
  unsigned short* q_ws  = (unsigned short*)(ws + 13631488);      // 8 MB
  unsigned short* k_ws  = (unsigned short*)(ws + 22020096);      // 2 MB
  unsigned short* vt_ws = (unsigned short*)(ws + 24117248);      // 2 MB
  unsigned char*  mflg  = (unsigned char*)(ws + 26214400);       // 2 KB

  k_prep<<<dim3(8704), dim3(256), 0, stream>>>(x, Wq, Wk, Wv, Wo, mask, xb, wcat, wo_b, mflg);
  k_gemm<0, 64><<<dim3(12, 64), dim3(256), 0, stream>>>(xb, wcat, bq, bk, bv, q_ws, k_ws, vt_ws, nullptr);
  k_attn<<<dim3(8, 64), dim3(512), 0, stream>>>(q_ws, k_ws, vt_ws, mask, mflg, ctx);
  k_gemm<1, 128><<<dim3(8, 32), dim3(256), 0, stream>>>(ctx, wo_b, bo, nullptr, nullptr,
                                                        nullptr, nullptr, nullptr, out);
}

// Round 15
// 103.974 us; speedup vs baseline: 5.9320x; 1.0083x over previous
//
#include <hip/hip_runtime.h>

#define B_   2
#define L_   2048
#define H_   1024
#define NH_  16
#define KVH_ 4
#define HD_  64

typedef short short8 __attribute__((ext_vector_type(8)));
typedef float f32x4 __attribute__((ext_vector_type(4)));
typedef float f32x16 __attribute__((ext_vector_type(16)));
typedef unsigned short u16x4 __attribute__((ext_vector_type(4)));

#define LOG2E 1.4426950408889634f
#define QSC   0.18033688011112042f   /* 0.125 * log2(e) */
#define MFMA   __builtin_amdgcn_mfma_f32_16x16x32_bf16
#define MFMA32 __builtin_amdgcn_mfma_f32_32x32x16_bf16

#if __has_builtin(__builtin_amdgcn_exp2f)
#define EXP2(x) __builtin_amdgcn_exp2f(x)
#else
#define EXP2(x) exp2f(x)
#endif

static __device__ __forceinline__ unsigned short f2bf(float f) {
  unsigned int u = __float_as_uint(f);
  u += 0x7FFFu + ((u >> 16) & 1u);
  return (unsigned short)(u >> 16);
}

static __device__ __forceinline__ unsigned int cvtpk(float lo, float hi) {
  unsigned int r;
  asm("v_cvt_pk_bf16_f32 %0, %1, %2" : "=v"(r) : "v"(lo), "v"(hi));
  return r;
}

// dst' = {dst.lo32lanes, src.lo32lanes}, src' = {dst.hi32lanes, src.hi32lanes}
static __device__ __forceinline__ void plswap(unsigned int& a, unsigned int& b) {
  asm("v_permlane32_swap_b32 %0, %1" : "+v"(a), "+v"(b));
}

static __device__ __forceinline__ short8 mk8(unsigned int w0, unsigned int w1,
                                             unsigned int w2, unsigned int w3) {
  union { unsigned int u[4]; short8 s; } x;
  x.u[0] = w0; x.u[1] = w1; x.u[2] = w2; x.u[3] = w3;
  return x.s;
}

static __device__ __forceinline__ void gload_lds16(const void* g, void* l) {
  __builtin_amdgcn_global_load_lds(
      (const __attribute__((address_space(1))) unsigned int*)g,
      (__attribute__((address_space(3))) unsigned int*)l, 16, 0, 0);
}

// counted vmcnt wait (literal must be compile-time)
template <int N> static __device__ __forceinline__ void waitcnt_vm() {
  if constexpr (N == 0)      asm volatile("s_waitcnt vmcnt(0)" ::: "memory");
  else if constexpr (N == 6) asm volatile("s_waitcnt vmcnt(6)" ::: "memory");
  else if constexpr (N == 8) asm volatile("s_waitcnt vmcnt(8)" ::: "memory");
  else                       asm volatile("s_waitcnt vmcnt(0)" ::: "memory");
}

// ---------------- merged prep: convert x, convert weights, mask scan ----------------
__global__ __launch_bounds__(256) void k_prep(const float* __restrict__ x,
                                              const float* __restrict__ Wq,
                                              const float* __restrict__ Wk,
                                              const float* __restrict__ Wv,
                                              const float* __restrict__ Wo,
                                              const float* __restrict__ mask,
                                              unsigned short* __restrict__ xb,
                                              unsigned short* __restrict__ wcat,
                                              unsigned short* __restrict__ wo_b,
                                              unsigned char* __restrict__ flags) {
  const int blk = blockIdx.x;
  const int t = threadIdx.x;
  if (blk < 4096) {                       // ---- convert x ----
    size_t i = ((size_t)blk * 256 + t) * 4;
    float4 v = *(const float4*)(x + i);
    u16x4 o = { f2bf(v.x), f2bf(v.y), f2bf(v.z), f2bf(v.w) };
    *(u16x4*)(xb + i) = o;
  } else if (blk < 6656) {                // ---- convert weights ----
    int r = blk - 4096;
    int c = t * 4;
    const float* src;
    unsigned short* dst;
    if (r < 1024)      { src = Wq + (size_t)r * 1024;          dst = wcat + (size_t)r * 1024; }
    else if (r < 1280) { src = Wk + (size_t)(r - 1024) * 1024; dst = wcat + (size_t)r * 1024; }
    else if (r < 1536) { src = Wv + (size_t)(r - 1280) * 1024; dst = wcat + (size_t)r * 1024; }
    else               { src = Wo + (size_t)(r - 1536) * 1024; dst = wo_b + (size_t)(r - 1536) * 1024; }
    float4 v = *(const float4*)(src + c);
    u16x4 o = { f2bf(v.x), f2bf(v.y), f2bf(v.z), f2bf(v.w) };
    *(u16x4*)(dst + c) = o;
  } else {                                // ---- mask block-zero scan ----
    const int mb = blk - 6656;            // b*1024 + qb*32 + kb
    const int b = mb >> 10, qb = (mb >> 5) & 31, kb = mb & 31;
    const float* base = mask + ((size_t)b * L_ + qb * 64) * L_ + kb * 64;
    const int r0 = t >> 4, c = (t & 15) * 4;
    bool nz = false;
#pragma unroll
    for (int i = 0; i < 4; ++i) {
      float4 v = *(const float4*)(base + (size_t)(r0 + i * 16) * L_ + c);
      nz |= (v.x != 0.f) | (v.y != 0.f) | (v.z != 0.f) | (v.w != 0.f);
    }
    __shared__ int anyv;
    if (t == 0) anyv = 0;
    __syncthreads();
    if (__any(nz) && (t & 63) == 0) atomicOr(&anyv, 1);
    __syncthreads();
    if (t == 0) flags[mb] = (unsigned char)anyv;
  }
}

// ---------------- GEMM (BMx128, BK=64, XOR-swizzle, 2-phase dbuf, COUNTED vmcnt) ----------------
// T4: raw barriers, never drain vmcnt to 0 mid-loop. Per iter: GSTAGE(next) -> wait
// vmcnt(NLOADS) (previous tile's loads done; the NLOADS just issued stay in flight) ->
// barrier -> compute(cur) -> lgkmcnt(0) -> barrier. The buffer overwritten by GSTAGE
// was last read an iteration ago (fenced by that iter's lgkm-barrier).
template <int MODE, int BM>
__global__ __launch_bounds__(256, BM == 64 ? 3 : 2)
void k_gemm(const unsigned short* __restrict__ A,
            const unsigned short* __restrict__ Bt,
            const float* __restrict__ bias0,
            const float* __restrict__ bias1,
            const float* __restrict__ bias2,
            unsigned short* __restrict__ q_ws,
            unsigned short* __restrict__ k_ws,
            unsigned short* __restrict__ vt_ws,
            float* __restrict__ outp) {
  constexpr int MR = BM / 32;             // M-frags per wave (wave covers BM/2 rows)
  constexpr int ACH = BM * 8 / 256;       // A staging chunks
  constexpr int NLOADS = ACH + 4;         // gload_lds per GSTAGE per thread
  const int bn = blockIdx.x, bm = blockIdx.y;
  const int t = threadIdx.x;
  const int lane = t & 63, li = lane & 15, g = lane >> 4;
  const int wid = t >> 6, wr = wid >> 1, wc = wid & 1;
  __shared__ unsigned short lds_a[2][BM * 64];    // [buf][row][slot], slot s = G col s^(row&7)
  __shared__ unsigned short lds_b[2][128 * 64];

  const f32x4 z = {0.f, 0.f, 0.f, 0.f};
  f32x4 acc[MR][4];
#pragma unroll
  for (int m = 0; m < MR; ++m)
#pragma unroll
    for (int n = 0; n < 4; ++n) acc[m][n] = z;

  const unsigned short* asrc[ACH];
  const unsigned short* bsrc[4];
  int adst[ACH], bdst[4];
#pragma unroll
  for (int c = 0; c < ACH; ++c) {
    const int idx = c * 256 + t, row = idx >> 3, sl = idx & 7;
    asrc[c] = A + (size_t)(bm * BM + row) * 1024 + ((sl ^ (row & 7)) * 8);
    adst[c] = idx * 8;
  }
#pragma unroll
  for (int c = 0; c < 4; ++c) {
    const int idx = c * 256 + t, row = idx >> 3, sl = idx & 7;
    bsrc[c] = Bt + (size_t)(bn * 128 + row) * 1024 + ((sl ^ (row & 7)) * 8);
    bdst[c] = idx * 8;
  }
  const int rs = li & 7;

#define GSTAGE(buf, kc)                                                  \
  {                                                                      \
    _Pragma("unroll")                                                    \
    for (int c = 0; c < ACH; ++c) gload_lds16(asrc[c] + (kc), &lds_a[buf][adst[c]]); \
    _Pragma("unroll")                                                    \
    for (int c = 0; c < 4; ++c)   gload_lds16(bsrc[c] + (kc), &lds_b[buf][bdst[c]]); \
  }

  GSTAGE(0, 0);                           // prologue loads in flight (no drain)

#pragma unroll 1
  for (int it = 0; it < 16; ++it) {
    const int cur = it & 1;
    if (it + 1 < 16) {
      GSTAGE(cur ^ 1, (it + 1) * 64);     // issue next tile first
      waitcnt_vm<NLOADS>();               // cur's loads done; next's stay in flight
    } else {
      waitcnt_vm<0>();                    // last tile: drain all
    }
    __builtin_amdgcn_s_barrier();         // cur readable by all waves
    __builtin_amdgcn_sched_barrier(0);
#pragma unroll
    for (int ks = 0; ks < 2; ++ks) {
      short8 af[MR], bf[4];
#pragma unroll
      for (int m = 0; m < MR; ++m)
        af[m] = *(const short8*)&lds_a[cur][(wr * (BM / 2) + m * 16 + li) * 64 +
                                            (((ks * 4 + g) ^ rs) * 8)];
#pragma unroll
      for (int n = 0; n < 4; ++n)
        bf[n] = *(const short8*)&lds_b[cur][(wc * 64 + n * 16 + li) * 64 +
                                            (((ks * 4 + g) ^ rs) * 8)];
#pragma unroll
      for (int m = 0; m < MR; ++m)
#pragma unroll
        for (int n = 0; n < 4; ++n)
          acc[m][n] = MFMA(af[m], bf[n], acc[m][n], 0, 0, 0);
    }
    asm volatile("s_waitcnt lgkmcnt(0)" ::: "memory");   // my reads of cur done
    __builtin_amdgcn_s_barrier();                        // everyone's reads done
    __builtin_amdgcn_sched_barrier(0);
  }
#undef GSTAGE

#pragma unroll
  for (int m = 0; m < MR; ++m) {
    const int row0 = bm * BM + wr * (BM / 2) + m * 16 + 4 * g;
#pragma unroll
    for (int n = 0; n < 4; ++n) {
      const int col = bn * 128 + wc * 64 + n * 16 + li;
      f32x4 v = acc[m][n];
      if (MODE == 1) {
        const float bias = bias0[col];
#pragma unroll
        for (int r = 0; r < 4; ++r) outp[(size_t)(row0 + r) * 1024 + col] = v[r] + bias;
      } else {
        if (col < 1024) {
          const float bias = bias0[col];
#pragma unroll
          for (int r = 0; r < 4; ++r) q_ws[(size_t)(row0 + r) * 1024 + col] = f2bf((v[r] + bias) * QSC);
        } else if (col < 1280) {
          const int cc = col - 1024;
          const float bias = bias1[cc];
#pragma unroll
          for (int r = 0; r < 4; ++r) k_ws[(size_t)(row0 + r) * 256 + cc] = f2bf(v[r] + bias);
        } else {
          const int cc = col - 1280;
          const float bias = bias2[cc];
          const int kvh = cc >> 6, d = cc & 63;
          const int b = row0 >> 11, l0 = row0 & 2047;
          u16x4 pk = { f2bf(v[0] + bias), f2bf(v[1] + bias), f2bf(v[2] + bias), f2bf(v[3] + bias) };
          *(u16x4*)(vt_ws + ((size_t)((b * KVH_ + kvh) * 64 + d)) * 2048 + l0) = pk;
        }
      }
    }
  }
}

// ---------------- flash attention (GQA, 8 waves: (kj-half, head), 32x32 MFMA, reg-P) ----------------
// R9 configuration (best measured: 48.4 us, VGPR 64, zero spill). grid (B*KVH=8, L/32=64),
// 512 threads, wave (kh,h): head h over kj-slice kh. T14 reg-staging (loads issued one
// iteration early -> vmcnt(0) free), raw lgkmcnt-only barriers (staged global loads stay
// in flight across the barrier), max-free softmax, in-register P (cvt_pk + permlane32_swap).
__global__ __launch_bounds__(512, 4) void k_attn(const unsigned short* __restrict__ q_ws,
                                                 const unsigned short* __restrict__ k_ws,
                                                 const unsigned short* __restrict__ vt_ws,
                                                 const float* __restrict__ mask,
                                                 const unsigned char* __restrict__ mflags,
                                                 unsigned short* __restrict__ ctx) {
  const int bk = blockIdx.x;            // b*4 + kvh (== XCD id -> L2 locality)
  const int qt = blockIdx.y;            // 32-row q tile
  const int b = bk >> 2, kvh = bk & 3;
  const int t = threadIdx.x;            // 0..511
  const int wid = t >> 6, lane = t & 63;
  const int l31 = lane & 31, g1 = lane >> 5;
  const int h = wid & 3, kh = wid >> 2;

  __shared__ unsigned short smem[16384];   // 32KB: 2 bufs x [K 8KB | V 8KB]
  __shared__ float lred[4][64];            // [h][lane] l partials from kh=1

  // ---- Q frags: B-operand of 32x32x16: n=q=l31, k=d = ks*16 + g1*8 + j ----
  const unsigned short* qbase = q_ws + ((size_t)b * L_ + qt * 32 + l31) * H_ +
                                (kvh * 4 + h) * 64 + g1 * 8;
  short8 qf[4];
#pragma unroll
  for (int ks = 0; ks < 4; ++ks) qf[ks] = *(const short8*)(qbase + ks * 16);

  // ---- mask flags -> register bitmask ----
  const unsigned int* fp = (const unsigned int*)(mflags + b * 1024 + (qt >> 1) * 32);
  unsigned int fm = 0;
#pragma unroll
  for (int w = 0; w < 8; ++w) {
    unsigned int wv = fp[w];
    fm |= ((wv & 0x000000FFu) ? 1u : 0u) << (w * 4 + 0);
    fm |= ((wv & 0x0000FF00u) ? 1u : 0u) << (w * 4 + 1);
    fm |= ((wv & 0x00FF0000u) ? 1u : 0u) << (w * 4 + 2);
    fm |= ((wv & 0xFF000000u) ? 1u : 0u) << (w * 4 + 3);
  }
  fm = __builtin_amdgcn_readfirstlane(fm);

  // ---- staging sources (pre-swizzled granules, rule #21); thread t: row t>>3, slot t&7 ----
  const int srow = t >> 3, sgr = t & 7;
  const int swz = (sgr ^ (srow & 7)) * 8;
  const unsigned short* ksrc = k_ws + ((size_t)b * L_ + srow) * 256 + kvh * 64 + swz;
  const unsigned short* vsrc = vt_ws + ((size_t)(b * KVH_ + kvh) * 64 + srow) * 2048 + swz;

  const f32x16 z16 = {0,0,0,0,0,0,0,0,0,0,0,0,0,0,0,0};
  f32x16 o_[2];                           // [db] : O^T[d = db*32 + row][q]
  o_[0] = z16; o_[1] = z16;
  float l_part = 0.f;

  const int rK = kh * 32 + l31, swK = rK & 7;
  const int swV = l31 & 7;                // (db*32 + l31) & 7, both db

  short8 kst, vst;                        // staged regs (tile kt+1)
#define LOADR(kt) { kst = *(const short8*)(ksrc + (size_t)(kt) * 16384); \
                    vst = *(const short8*)(vsrc + (kt) * 64); }
#define WRITES(buf) { unsigned short* dk = smem + (buf) * 8192;          \
                      *(short8*)(dk + t * 8) = kst;                      \
                      *(short8*)(dk + 4096 + t * 8) = vst; }

  // prologue: buf0 = tile 0 (visible), regs = tile 1 (may be in flight)
  LOADR(0);
  WRITES(0);                              // compiler waits vmcnt for kst/vst use
  LOADR(1);
  __syncthreads();                        // one full drain; invariant established

#pragma unroll 1
  for (int kt = 0; kt < 32; ++kt) {
    const int cur = kt & 1;
    const unsigned short* lk = smem + cur * 8192;
    const unsigned short* lv = lk + 4096;

    // ---- K/V frags of tile kt ----
    short8 kf[4];
#pragma unroll
    for (int ks = 0; ks < 4; ++ks)
      kf[ks] = *(const short8*)&lk[rK * 64 + ((ks * 2 + g1) ^ swK) * 8];
    short8 vf[2][2];
#pragma unroll
    for (int db = 0; db < 2; ++db)
#pragma unroll
      for (int s = 0; s < 2; ++s)
        vf[db][s] = *(const short8*)&lv[(db * 32 + l31) * 64 + ((kh * 4 + s * 2 + g1) ^ swV) * 8];

    // ---- T14: regs(kt+1) landed (issued a full iter ago) -> write-late, then issue kt+2
    asm volatile("s_waitcnt vmcnt(0)" ::: "memory");
    if (kt + 1 < 32) WRITES(cur ^ 1);
    if (kt + 2 < 32) LOADR(kt + 2);

    // ---- S^T[32kj x 32q] = K * Q^T ----
    f32x16 sv = z16;
    __builtin_amdgcn_s_setprio(1);
#pragma unroll
    for (int ks = 0; ks < 4; ++ks) sv = MFMA32(kf[ks], qf[ks], sv, 0, 0, 0);
    __builtin_amdgcn_s_setprio(0);

    if (fm & (1u << kt)) {                 // rare: mask block nonzero
      const float* mrow = mask + ((size_t)b * L_ + qt * 32 + l31) * L_ + kt * 64 + kh * 32 + g1 * 4;
#pragma unroll
      for (int rg = 0; rg < 4; ++rg) {
        float4 mv = *(const float4*)(mrow + rg * 8);
#pragma unroll
        for (int j = 0; j < 4; ++j) sv[rg * 4 + j] = fmaf((&mv.x)[j], LOG2E, sv[rg * 4 + j]);
      }
    }

    // ---- max-free softmax + in-register P re-layout (cvt_pk + permlane32_swap) ----
    float e[16];
#pragma unroll
    for (int r = 0; r < 16; ++r) e[r] = EXP2(sv[r]);
    l_part += (((e[0] + e[1]) + (e[2] + e[3])) + ((e[4] + e[5]) + (e[6] + e[7]))) +
              (((e[8] + e[9]) + (e[10] + e[11])) + ((e[12] + e[13]) + (e[14] + e[15])));
    unsigned int w0 = cvtpk(e[0], e[1]),   w1 = cvtpk(e[2], e[3]);
    unsigned int w2 = cvtpk(e[4], e[5]),   w3 = cvtpk(e[6], e[7]);
    unsigned int w4 = cvtpk(e[8], e[9]),   w5 = cvtpk(e[10], e[11]);
    unsigned int w6 = cvtpk(e[12], e[13]), w7 = cvtpk(e[14], e[15]);
    plswap(w0, w2); plswap(w1, w3);        // kstep 0
    plswap(w4, w6); plswap(w5, w7);        // kstep 1
    short8 pa0 = mk8(w0, w1, w2, w3);
    short8 pa1 = mk8(w4, w5, w6, w7);

    // ---- PV: O^T[d][q] += V^T * P^T ----
    __builtin_amdgcn_s_setprio(1);
#pragma unroll
    for (int db = 0; db < 2; ++db) {
      o_[db] = MFMA32(vf[db][0], pa0, o_[db], 0, 0, 0);
      o_[db] = MFMA32(vf[db][1], pa1, o_[db], 0, 0, 0);
    }
    __builtin_amdgcn_s_setprio(0);

    // ---- raw barrier: ds_writes visible; kt+2 global loads stay in flight ----
    asm volatile("s_waitcnt lgkmcnt(0)" ::: "memory");
    __builtin_amdgcn_s_barrier();
    __builtin_amdgcn_sched_barrier(0);
  }
#undef LOADR
#undef WRITES

  // ---- epilogue: merge kh partials via LDS (coalesced 16B/lane layout) ----
  float lt = l_part + __shfl_xor(l_part, 32);
  float* red = (float*)smem;              // reuse: [(h*2+db)*4 + w4][lane][4]

  if (kh == 1) {
    lred[h][lane] = lt;
#pragma unroll
    for (int db = 0; db < 2; ++db)
#pragma unroll
      for (int w4 = 0; w4 < 4; ++w4) {
        f32x4 pv = { o_[db][w4 * 4 + 0], o_[db][w4 * 4 + 1],
                     o_[db][w4 * 4 + 2], o_[db][w4 * 4 + 3] };
        *(f32x4*)&red[(((h * 2 + db) * 4 + w4) * 64 + lane) * 4] = pv;
      }
  }
  __syncthreads();

  if (kh == 0) {
    const float inv = 1.f / (lt + lred[h][lane]);
#pragma unroll
    for (int db = 0; db < 2; ++db) {
      f32x16 acc = o_[db];
#pragma unroll
      for (int w4 = 0; w4 < 4; ++w4) {
        f32x4 pv = *(const f32x4*)&red[(((h * 2 + db) * 4 + w4) * 64 + lane) * 4];
#pragma unroll
        for (int j = 0; j < 4; ++j) acc[w4 * 4 + j] += pv[j];
      }
      unsigned short* cp = ctx + ((size_t)b * L_ + qt * 32 + l31) * H_ +
                           (kvh * 4 + h) * 64 + db * 32 + g1 * 4;
#pragma unroll
      for (int k4 = 0; k4 < 4; ++k4) {
        unsigned int a0 = cvtpk(acc[4 * k4 + 0] * inv, acc[4 * k4 + 1] * inv);
        unsigned int a1 = cvtpk(acc[4 * k4 + 2] * inv, acc[4 * k4 + 3] * inv);
        *(unsigned int*)(cp + 8 * k4) = a0;
        *(unsigned int*)(cp + 8 * k4 + 2) = a1;
      }
    }
  }
}

// ---------------- launch ----------------
extern "C" void kernel_launch(void* const* d_in, const int* in_sizes, int n_in,
                              void* d_out, int out_size, void* d_ws, size_t ws_size,
                              hipStream_t stream) {
  const float* x    = (const float*)d_in[0];
  const float* mask = (const float*)d_in[1];
  const float* Wq   = (const float*)d_in[2];
  const float* bq   = (const float*)d_in[3];
  const float* Wk   = (const float*)d_in[4];
  const float* bk   = (const float*)d_in[5];
  const float* Wv   = (const float*)d_in[6];
  const float* bv   = (const float*)d_in[7];
  const float* Wo   = (const float*)d_in[8];
  const float* bo   = (const float*)d_in[9];
  float* out = (float*)d_out;

  char* ws = (char*)d_ws;
  unsigned short* xb    = (unsigned short*)(ws);                 // 8 MB (reused as ctx)
  unsigned short* ctx   = xb;
  unsigned short* wcat  = (unsigned short*)(ws + 8388608);       // 3 MB
  unsigned short* wo_b  = (unsigned short*)(ws + 11534336);      // 2 MB
  unsigned short* q_ws  = (unsigned short*)(ws + 13631488);      // 8 MB
  unsigned short* k_ws  = (unsigned short*)(ws + 22020096);      // 2 MB
  unsigned short* vt_ws = (unsigned short*)(ws + 24117248);      // 2 MB
  unsigned char*  mflg  = (unsigned char*)(ws + 26214400);       // 2 KB

  k_prep<<<dim3(8704), dim3(256), 0, stream>>>(x, Wq, Wk, Wv, Wo, mask, xb, wcat, wo_b, mflg);
  k_gemm<0, 64><<<dim3(12, 64), dim3(256), 0, stream>>>(xb, wcat, bq, bk, bv, q_ws, k_ws, vt_ws, nullptr);
  k_attn<<<dim3(8, 64), dim3(512), 0, stream>>>(q_ws, k_ws, vt_ws, mask, mflg, ctx);
  k_gemm<1, 128><<<dim3(8, 32), dim3(256), 0, stream>>>(ctx, wo_b, bo, nullptr, nullptr,
                                                        nullptr, nullptr, nullptr, out);
}